// Round 9
// baseline (217.000 us; speedup 1.0000x reference)
//
#include <hip/hip_runtime.h>

// VQ-VAE vector quantize + losses, MI355X.
// T=8192 rows, N_E=16384 codes, D=32.
// R24: R23 regressed (2x blocks -> 2x epilogue cost; occupancy lever dead
//      4 rounds running). LDS-pipe audit of R22: ds_read 49K + gload-write
//      8K + epilogue ds_bpermute 30K ~= 87K cyc/CU vs 129K wall -> the
//      CU-shared LDS pipe is the dominant consumer; epilogue shuffles are
//      1/3 of it only because i1/i2 ride along. R24 = R22 geometry with:
//      - keys pack (tile<<4)|c in 10 mantissa LSBs -> shuffle only
//        m1/m2/Zs (3 vars, merge = max/min/max), decode indices after.
//        fb quantized to 13-bit mantissa; k_mf exact refine re-ranks.
//      - zred + mf-main merged into k_zm (64 blocks); final scalars moved
//        into pass2's last block (counter 1023). 4 launches total.
//      Tripwires: absmax ~2.44e-4 (packing changes tie-breaks only);
//      pass1 WRITE ~2.5MB; >=52us clean kills the LDS-pipe model too.

#define N_E 16384
#define ED 32
#define T 8192
#define NS1 16      // pass-1 code splits (1024 codes each)
#define RS2 8       // pass-2 row splits  (1024 rows each)
#define SKIPM -36.0f
#define PHT 8       // tiles per staged phase (16KB)

#define K2 288.53900817779268f      // 200 * log2(e)
#define NS2F -144.26950408889634f   // -100 * log2(e)
#define BIAS1 -208.53900817779268f  // 80 + 2*NS2F
#define SC2C -64.26950408889634f    // 80 + NS2F
#define LN2 0.6931471805599453f

typedef __attribute__((ext_vector_type(8))) short s16x8;
typedef __attribute__((ext_vector_type(4))) float f32x4;

__device__ __forceinline__ float fexp2(float x) { return __builtin_amdgcn_exp2f(x); }
__device__ __forceinline__ float flog2(float x) { return __builtin_amdgcn_logf(x); }
__device__ __forceinline__ float fmed3(float a, float b, float c) {
  return __builtin_amdgcn_fmed3f(a, b, c);
}

// async global->LDS, 16B per lane; LDS dest = wave-uniform base + lane*16.
__device__ __forceinline__ void gload16(const void* g, void* l) {
  __builtin_amdgcn_global_load_lds(
      (const __attribute__((address_space(1))) void*)g,
      (__attribute__((address_space(3))) void*)l, 16, 0, 0);
}

__device__ __forceinline__ unsigned short f2bf(float x) {
  unsigned u = __float_as_uint(x);
  unsigned r = (u + 0x7FFFu + ((u >> 16) & 1u)) >> 16;
  return (unsigned short)r;
}
__device__ __forceinline__ float bf2f(unsigned short h) {
  return __uint_as_float(((unsigned)h) << 16);
}

// exact fp32 dot of a streamed row with 8 resident float4s (by value)
__device__ __forceinline__ float dot32x(const float* __restrict__ p,
    float4 z0, float4 z1, float4 z2, float4 z3,
    float4 z4, float4 z5, float4 z6, float4 z7) {
  const float4* e = (const float4*)p;
  float a0 = 0.f, a1 = 0.f, a2 = 0.f, a3 = 0.f; float4 q;
  q = e[0]; a0 = fmaf(q.x, z0.x, a0); a0 = fmaf(q.y, z0.y, a0);
            a0 = fmaf(q.z, z0.z, a0); a0 = fmaf(q.w, z0.w, a0);
  q = e[1]; a1 = fmaf(q.x, z1.x, a1); a1 = fmaf(q.y, z1.y, a1);
            a1 = fmaf(q.z, z1.z, a1); a1 = fmaf(q.w, z1.w, a1);
  q = e[2]; a2 = fmaf(q.x, z2.x, a2); a2 = fmaf(q.y, z2.y, a2);
            a2 = fmaf(q.z, z2.z, a2); a2 = fmaf(q.w, z2.w, a2);
  q = e[3]; a3 = fmaf(q.x, z3.x, a3); a3 = fmaf(q.y, z3.y, a3);
            a3 = fmaf(q.z, z3.z, a3); a3 = fmaf(q.w, z3.w, a3);
  q = e[4]; a0 = fmaf(q.x, z4.x, a0); a0 = fmaf(q.y, z4.y, a0);
            a0 = fmaf(q.z, z4.z, a0); a0 = fmaf(q.w, z4.w, a0);
  q = e[5]; a1 = fmaf(q.x, z5.x, a1); a1 = fmaf(q.y, z5.y, a1);
            a1 = fmaf(q.z, z5.z, a1); a1 = fmaf(q.w, z5.w, a1);
  q = e[6]; a2 = fmaf(q.x, z6.x, a2); a2 = fmaf(q.y, z6.y, a2);
            a2 = fmaf(q.z, z6.z, a2); a2 = fmaf(q.w, z6.w, a2);
  q = e[7]; a3 = fmaf(q.x, z7.x, a3); a3 = fmaf(q.y, z7.y, a3);
            a3 = fmaf(q.z, z7.z, a3); a3 = fmaf(q.w, z7.w, a3);
  return (a0 + a1) + (a2 + a3);
}

// split 8 floats (scaled by sc) of row `row`, group g into hi/lo bf16 frags,
// stored TILE-MAJOR: dst[tile*128 + g*16 + c] (hi), +64 (lo); s16x8 units.
__device__ __forceinline__ void split_store_t(short* __restrict__ base,
    int row, int g, float4 va, float4 vb, float sc) {
  float f[8] = { va.x * sc, va.y * sc, va.z * sc, va.w * sc,
                 vb.x * sc, vb.y * sc, vb.z * sc, vb.w * sc };
  s16x8 H, L;
#pragma unroll
  for (int e = 0; e < 8; ++e) {
    unsigned short h = f2bf(f[e]);
    H[e] = (short)h;
    L[e] = (short)f2bf(f[e] - bf2f(h));
  }
  s16x8* p = (s16x8*)base;
  const int tile = row >> 4, c = row & 15;
  p[tile * 128 + g * 16 + c] = H;
  p[tile * 128 + 64 + g * 16 + c] = L;
}

// --- prep: blocks 0..63 emb rows; 64..95 z transpose; 96..160 zero avg/scal ---
__global__ __launch_bounds__(256) void k_prep(const float* __restrict__ emb,
    const float* __restrict__ z, float* __restrict__ embn,
    float* __restrict__ ses2, float* __restrict__ zf, float* __restrict__ a02,
    short* __restrict__ ehl, short* __restrict__ zhl, float* __restrict__ avg,
    float* __restrict__ scal) {
  if (blockIdx.x < 64) {
    int n = blockIdx.x * 256 + threadIdx.x;
    const float4* r4 = (const float4*)(emb + (size_t)n * ED);
    float4 v[8]; float s = 0.f;
#pragma unroll
    for (int j = 0; j < 8; ++j) {
      v[j] = r4[j];
      s = fmaf(v[j].x, v[j].x, s); s = fmaf(v[j].y, v[j].y, s);
      s = fmaf(v[j].z, v[j].z, s); s = fmaf(v[j].w, v[j].w, s);
    }
    float inv = 1.0f / fmaxf(sqrtf(s), 1e-12f);
    float s2 = 0.f;
    float4* o4 = (float4*)(embn + (size_t)n * ED);
#pragma unroll
    for (int j = 0; j < 8; ++j) {
      float4 w; w.x = v[j].x * inv; w.y = v[j].y * inv;
      w.z = v[j].z * inv; w.w = v[j].w * inv;
      o4[j] = w; v[j] = w;
      s2 = fmaf(w.x, w.x, s2); s2 = fmaf(w.y, w.y, s2);
      s2 = fmaf(w.z, w.z, s2); s2 = fmaf(w.w, w.w, s2);
    }
    ses2[n] = NS2F * s2;               // true value, for the exact refine
#pragma unroll
    for (int g = 0; g < 4; ++g)
      split_store_t(ehl, n, g, v[2 * g], v[2 * g + 1], 1.0f);
  } else if (blockIdx.x < 96) {
    int t = (blockIdx.x - 64) * 256 + threadIdx.x;
    int b = t >> 8, hw = t & 255;
    const float* base = z + (size_t)b * (ED * 256) + hw;
    float4 v[8]; float s = 0.f;
#pragma unroll
    for (int j = 0; j < 8; ++j) {
      float4 w;
      w.x = base[(4 * j + 0) * 256]; w.y = base[(4 * j + 1) * 256];
      w.z = base[(4 * j + 2) * 256]; w.w = base[(4 * j + 3) * 256];
      v[j] = w;
      s = fmaf(w.x, w.x, s); s = fmaf(w.y, w.y, s);
      s = fmaf(w.z, w.z, s); s = fmaf(w.w, w.w, s);
    }
    float inv = 1.0f / fmaxf(sqrtf(s), 1e-12f);
    float s2 = 0.f;
    float4* o4 = (float4*)(zf + (size_t)t * ED);
#pragma unroll
    for (int j = 0; j < 8; ++j) {
      float4 w; w.x = v[j].x * inv; w.y = v[j].y * inv;
      w.z = v[j].z * inv; w.w = v[j].w * inv;
      o4[j] = w; v[j] = w;
      s2 = fmaf(w.x, w.x, s2); s2 = fmaf(w.y, w.y, s2);
      s2 = fmaf(w.z, w.z, s2); s2 = fmaf(w.w, w.w, s2);
    }
    a02[t] = NS2F * s2;               // only k_zm (exact refine) uses this
#pragma unroll
    for (int g = 0; g < 4; ++g)
      split_store_t(zhl, t, g, v[2 * g], v[2 * g + 1], K2);
  } else if (blockIdx.x < 160) {
    avg[(blockIdx.x - 96) * 256 + threadIdx.x] = 0.f;
  } else {
    if (threadIdx.x < 4) scal[threadIdx.x] = 0.f;  // [0]=sampE [1]=vq [2]=cnt
  }
}

// --- pass 1: block = 128 rows (4 waves x 32 = 2 A-pairs each), sweeps a
//     1024-code split (64 tiles, 8 phases x 8). B staged via gload_lds
//     into 2x16KB dbuf. Bias = const 80+2*NS2F. Top-2 via keys packing
//     (tile<<4)|c in 10 mantissa LSBs -> epilogue shuffles only m1/m2/Zs.
__global__ __launch_bounds__(256, 4) void k_pass1(
    const short* __restrict__ ehl, const short* __restrict__ zhl,
    float* __restrict__ pm1, float* __restrict__ pm2, float* __restrict__ pZ,
    int* __restrict__ pi1, int* __restrict__ pi2) {
  const int tid = threadIdx.x;
  const int lane = tid & 63, wv = tid >> 6;
  const int q = lane >> 4, c = lane & 15;
  const int rowbase = blockIdx.x * 128 + wv * 32;
  const int nb0 = blockIdx.y * (N_E / NS1);
  const int NT = (N_E / NS1) / 16;  // 64
  const int NP = NT / PHT;          // 8

  __shared__ s16x8 dbuf[2][PHT * 128];   // 2 x 16KB

  const s16x8* zg = (const s16x8*)zhl;
  const int atile = rowbase >> 4;
  s16x8 ah[2], al[2];
#pragma unroll
  for (int rg = 0; rg < 2; ++rg) {
    ah[rg] = zg[(atile + rg) * 128 + lane];
    al[rg] = zg[(atile + rg) * 128 + 64 + lane];
  }

  f32x4 bias;
#pragma unroll
  for (int r = 0; r < 4; ++r) bias[r] = BIAS1;

  float m1[2][4], m2[2][4], Zs[2][4];
#pragma unroll
  for (int rg = 0; rg < 2; ++rg)
#pragma unroll
    for (int k = 0; k < 4; ++k) {
      m1[rg][k] = -1e30f; m2[rg][k] = -1e30f; Zs[rg][k] = 0.f;
    }

  const s16x8* eg = (const s16x8*)ehl + (size_t)(nb0 >> 4) * 128;

  // stage phase 0: 16KB; wave wv covers s16x8 [wv*256, wv*256+256)
#pragma unroll
  for (int j = 0; j < 4; ++j)
    gload16(eg + wv * 256 + j * 64 + lane, &dbuf[0][wv * 256 + j * 64]);
  __syncthreads();

  for (int p = 0; p < NP; ++p) {
    if (p + 1 < NP) {
      const s16x8* gs = eg + (p + 1) * (PHT * 128);
      s16x8* lb = &dbuf[(p + 1) & 1][0];
#pragma unroll
      for (int j = 0; j < 4; ++j)
        gload16(gs + wv * 256 + j * 64 + lane, lb + wv * 256 + j * 64);
    }
    const s16x8* bb = &dbuf[p & 1][0];
#pragma unroll
    for (int tt = 0; tt < PHT; ++tt) {
      s16x8 bh = bb[tt * 128 + lane], bl = bb[tt * 128 + 64 + lane];
      const unsigned tu = (unsigned)(p * PHT + tt);       // 0..63
      const unsigned tuc = (tu << 4) | (unsigned)c;       // 10-bit id
#pragma unroll
      for (int rg = 0; rg < 2; ++rg) {
        f32x4 acc = __builtin_amdgcn_mfma_f32_16x16x32_bf16(ah[rg], bh, bias, 0, 0, 0);
        acc = __builtin_amdgcn_mfma_f32_16x16x32_bf16(al[rg], bh, acc, 0, 0, 0);
        acc = __builtin_amdgcn_mfma_f32_16x16x32_bf16(ah[rg], bl, acc, 0, 0, 0);
#pragma unroll
        for (int r = 0; r < 4; ++r) {
          float fb = acc[r];
          float key = __uint_as_float((__float_as_uint(fb) & 0xFFFFFC00u) | tuc);
          m2[rg][r] = fmed3(key, m1[rg][r], m2[rg][r]);
          m1[rg][r] = fmaxf(m1[rg][r], key);
          Zs[rg][r] += fexp2(fb);
        }
      }
    }
    __syncthreads();
  }

  // 16-lane reduce on packed keys only (indices decoded after)
#pragma unroll
  for (int d = 1; d < 16; d <<= 1) {
#pragma unroll
    for (int rg = 0; rg < 2; ++rg)
#pragma unroll
      for (int k = 0; k < 4; ++k) {
        float o1 = __shfl_xor(m1[rg][k], d);
        float o2 = __shfl_xor(m2[rg][k], d);
        float oZ = __shfl_xor(Zs[rg][k], d);
        float lo = fminf(m1[rg][k], o1);
        m1[rg][k] = fmaxf(m1[rg][k], o1);
        m2[rg][k] = fmaxf(lo, fmaxf(m2[rg][k], o2));
        Zs[rg][k] += oZ;
      }
  }

#pragma unroll
  for (int rg = 0; rg < 2; ++rg)
#pragma unroll
    for (int k = 0; k < 4; ++k) {
      if (c == k) {
        const int t = rowbase + rg * 16 + q * 4 + k;
        const int p = blockIdx.y * T + t;
        const unsigned k1 = __float_as_uint(m1[rg][k]);
        const unsigned k2 = __float_as_uint(m2[rg][k]);
        pm1[p] = m1[rg][k]; pm2[p] = m2[rg][k]; pZ[p] = Zs[rg][k];
        pi1[p] = nb0 + (int)(((k1 >> 4) & 63u) << 4) + (int)(k1 & 15u);
        pi2[p] = nb0 + (int)(((k2 >> 4) & 63u) << 4) + (int)(k2 & 15u);
      }
    }
}

// --- zm: blocks 0..31 = zred (Z merge + lse, bias-free); blocks 32..63 =
//     mf-main (top-2 combine, exact refine, output, vq sum). Final scalars
//     moved into pass2's last block. ---
__global__ __launch_bounds__(256) void k_zm(const float* __restrict__ pZ,
    float* __restrict__ sc2g,
    const float* __restrict__ pm1, const float* __restrict__ pm2,
    const int* __restrict__ pi1, const int* __restrict__ pi2,
    const float* __restrict__ zf, const float* __restrict__ embn,
    const float* __restrict__ ses2, const float* __restrict__ a02,
    float* __restrict__ scal, float* __restrict__ out) {
  const int tid = threadIdx.x;
  if (blockIdx.x < 32) {
    const int t = blockIdx.x * 256 + tid;
    float Z = 0.f;
    for (int s = 0; s < NS1; ++s) Z += pZ[s * T + t];
    sc2g[t] = SC2C - flog2(Z);
    return;
  }
  const int t = (blockIdx.x - 32) * 256 + tid;
  __shared__ float red[256];

  float m1 = -1e30f, m2 = -1e30f;
  int i1 = 0, i2 = 0;
  for (int s = 0; s < NS1; ++s) {
    const int p = s * T + t;
    float sm1 = pm1[p], sm2 = pm2[p];
    int si1 = pi1[p], si2 = pi2[p];
    bool c1 = sm1 > m1;
    float lm = c1 ? m1 : sm1;
    int li = c1 ? i1 : si1;
    float nm1 = c1 ? sm1 : m1;
    int ni1 = c1 ? si1 : i1;
    bool cb = sm2 > m2;
    float mm2 = cb ? sm2 : m2;
    int mi2 = cb ? si2 : i2;
    bool c3 = mm2 > lm;
    m1 = nm1; i1 = ni1;
    m2 = c3 ? mm2 : lm;
    i2 = c3 ? mi2 : li;
  }
  const float a02t = a02[t];

  const float4* zr4 = (const float4*)(zf + (size_t)t * ED);
  float4 z0 = zr4[0], z1 = zr4[1], z2 = zr4[2], z3 = zr4[3];
  float4 z4 = zr4[4], z5 = zr4[5], z6 = zr4[6], z7 = zr4[7];
  float d1 = dot32x(embn + (size_t)i1 * ED, z0, z1, z2, z3, z4, z5, z6, z7);
  float d2 = dot32x(embn + (size_t)i2 * ED, z0, z1, z2, z3, z4, z5, z6, z7);
  float fb1 = fmaf(K2, d1, a02t + ses2[i1]);   // true a02/ses2: exact rule
  float fb2 = fmaf(K2, d2, a02t + ses2[i2]);
  int bi = (fb2 > fb1 || (fb2 == fb1 && i2 < i1)) ? i2 : i1;

  const int b = t >> 8, hw = t & 255;
  float* ob = out + (size_t)b * (ED * 256) + hw;
  float ss = 0.f;
  const float4* e4 = (const float4*)(embn + (size_t)bi * ED);
#pragma unroll
  for (int j = 0; j < 8; ++j) {
    float4 qv = e4[j];
    float4 zv = (j == 0) ? z0 : (j == 1) ? z1 : (j == 2) ? z2 : (j == 3) ? z3
              : (j == 4) ? z4 : (j == 5) ? z5 : (j == 6) ? z6 : z7;
    float df;
    df = qv.x - zv.x; ss = fmaf(df, df, ss); ob[(4 * j + 0) * 256] = zv.x + (qv.x - zv.x);
    df = qv.y - zv.y; ss = fmaf(df, df, ss); ob[(4 * j + 1) * 256] = zv.y + (qv.y - zv.y);
    df = qv.z - zv.z; ss = fmaf(df, df, ss); ob[(4 * j + 2) * 256] = zv.z + (qv.z - zv.z);
    df = qv.w - zv.w; ss = fmaf(df, df, ss); ob[(4 * j + 3) * 256] = zv.w + (qv.w - zv.w);
  }
  red[tid] = ss;
  __syncthreads();
  for (int st = 128; st > 0; st >>= 1) {
    if (tid < st) red[tid] += red[tid + st];
    __syncthreads();
  }
  if (tid == 0) atomicAdd(&scal[1], red[0]);
}

// --- pass 2: block = 128 codes (4 waves x 32 = 2 A-pairs), sweeps a
//     1024-row split. zhl staged (2x16KB dbuf); sc2 split (4KB) staged
//     once. Tile-skip: max(fb)+cc > -36. Last block computes final
//     scalars (counter on scal[2] -> 1023). ---
__global__ __launch_bounds__(256, 4) void k_pass2(
    const short* __restrict__ ehl, const short* __restrict__ zhl,
    const float* __restrict__ sc2g, float* __restrict__ avg,
    float* __restrict__ scal, float* __restrict__ out) {
  const int tid = threadIdx.x;
  const int lane = tid & 63, wv = tid >> 6;
  const int q = lane >> 4, c = lane & 15;
  const int bx = blockIdx.x & 127, by = blockIdx.x >> 7;
  const int tb0 = by * (T / RS2);
  const int cbase = bx * 128 + wv * 32;
  const int NT = (T / RS2) / 16;    // 64
  const int NP = NT / PHT;          // 8

  __shared__ s16x8 dbuf[2][PHT * 128];   // 32KB
  __shared__ float sc2l[T / RS2];        // 1024 f = 4KB
  __shared__ unsigned sord;

  ((float4*)sc2l)[tid] = ((const float4*)(sc2g + tb0))[tid];

  const s16x8* eg = (const s16x8*)ehl;
  const int atile = cbase >> 4;
  s16x8 ah[2], al[2];
#pragma unroll
  for (int rg = 0; rg < 2; ++rg) {
    ah[rg] = eg[(atile + rg) * 128 + lane];
    al[rg] = eg[(atile + rg) * 128 + 64 + lane];
  }

  f32x4 sg;
#pragma unroll
  for (int r = 0; r < 4; ++r) sg[r] = NS2F;

  float accP[2][4], accE[2][4];
#pragma unroll
  for (int rg = 0; rg < 2; ++rg)
#pragma unroll
    for (int k = 0; k < 4; ++k) { accP[rg][k] = 0.f; accE[rg][k] = 0.f; }

  const s16x8* zt = (const s16x8*)zhl + (size_t)(tb0 >> 4) * 128;

#pragma unroll
  for (int j = 0; j < 4; ++j)
    gload16(zt + wv * 256 + j * 64 + lane, &dbuf[0][wv * 256 + j * 64]);
  __syncthreads();

  for (int p = 0; p < NP; ++p) {
    if (p + 1 < NP) {
      const s16x8* gs = zt + (p + 1) * (PHT * 128);
      s16x8* lb = &dbuf[(p + 1) & 1][0];
#pragma unroll
      for (int j = 0; j < 4; ++j)
        gload16(gs + wv * 256 + j * 64 + lane, lb + wv * 256 + j * 64);
    }
    const s16x8* bb = &dbuf[p & 1][0];
#pragma unroll
    for (int tt = 0; tt < PHT; ++tt) {
      s16x8 bh = bb[tt * 128 + lane], bl = bb[tt * 128 + 64 + lane];
      float cc = sc2l[(p * PHT + tt) * 16 + c];
#pragma unroll
      for (int rg = 0; rg < 2; ++rg) {
        f32x4 acc = __builtin_amdgcn_mfma_f32_16x16x32_bf16(ah[rg], bh, sg, 0, 0, 0);
        acc = __builtin_amdgcn_mfma_f32_16x16x32_bf16(al[rg], bh, acc, 0, 0, 0);
        acc = __builtin_amdgcn_mfma_f32_16x16x32_bf16(ah[rg], bl, acc, 0, 0, 0);

        float m4 = fmaxf(fmaxf(acc[0], acc[1]), fmaxf(acc[2], acc[3]));
        if (__any(m4 + cc > SKIPM)) {
#pragma unroll
          for (int r = 0; r < 4; ++r) {
            float dl = acc[r] + cc;   // fb - lse (<=0)
            float pe = fexp2(dl);     // underflow -> 0
            accP[rg][r] += pe;
            accE[rg][r] = fmaf(pe, dl, accE[rg][r]);
          }
        }
      }
    }
    __syncthreads();
  }

  float etot = 0.f;
#pragma unroll
  for (int rg = 0; rg < 2; ++rg)
#pragma unroll
    for (int k = 0; k < 4; ++k) etot += accE[rg][k];

#pragma unroll
  for (int d = 1; d < 16; d <<= 1) {
#pragma unroll
    for (int rg = 0; rg < 2; ++rg)
#pragma unroll
      for (int k = 0; k < 4; ++k) accP[rg][k] += __shfl_xor(accP[rg][k], d);
  }
#pragma unroll
  for (int rg = 0; rg < 2; ++rg)
#pragma unroll
    for (int k = 0; k < 4; ++k) {
      if (c == k) atomicAdd(&avg[cbase + rg * 16 + q * 4 + k], accP[rg][k]);
    }

  float* red = sc2l;                 // sweep done; reuse LDS (post-barrier)
  __syncthreads();
  red[tid] = etot;
  __syncthreads();
  for (int st = 128; st > 0; st >>= 1) {
    if (tid < st) red[tid] += red[tid + st];
    __syncthreads();
  }
  if (tid == 0) atomicAdd(&scal[0], red[0]);

  // last-finished block computes final scalars (scal[1] from k_zm done)
  __threadfence();
  __syncthreads();
  if (tid == 0) sord = atomicAdd((unsigned*)&scal[2], 1u);
  __syncthreads();
  if (sord == (N_E / 128) * RS2 - 1) {
    float s = 0.f;
    for (int i = tid; i < N_E; i += 256) {
      float a = avg[i] * (1.0f / T);
      s += a * (flog2(a + 1e-5f) * LN2);
    }
    red[tid] = s;
    __syncthreads();
    for (int st = 128; st > 0; st >>= 1) {
      if (tid < st) red[tid] += red[tid + st];
      __syncthreads();
    }
    if (tid == 0) {
      float avg_entropy = -red[0];
      float se = __hip_atomic_load(&scal[0], __ATOMIC_RELAXED,
                                   __HIP_MEMORY_SCOPE_AGENT);
      float vqs = __hip_atomic_load(&scal[1], __ATOMIC_RELAXED,
                                    __HIP_MEMORY_SCOPE_AGENT);
      float sample_entropy = -(se * LN2) * (1.0f / T);
      float vq = vqs * (1.0f / (T * ED));
      out[T * ED + 0] = vq;
      out[T * ED + 1] = 0.25f * vq;
      out[T * ED + 2] = 0.1f * (sample_entropy - avg_entropy);
    }
  }
}

extern "C" void kernel_launch(void* const* d_in, const int* in_sizes, int n_in,
                              void* d_out, int out_size, void* d_ws, size_t ws_size,
                              hipStream_t stream) {
  const float* z = (const float*)d_in[0];
  const float* emb = (const float*)d_in[1];
  float* out = (float*)d_out;
  float* w = (float*)d_ws;

  float* embn = w;                          // 524288 f
  float* ses2 = embn + 524288;              // 16384
  float* zf   = ses2 + 16384;               // 262144
  float* a02  = zf + 262144;                // 8192
  short* ehl  = (short*)(a02 + 8192);       // 1048576 sh (524288 f)
  short* zhl  = ehl + 1048576;              // 524288 sh  (262144 f)
  float* pm1  = (float*)(zhl + 524288);     // NS1*T = 131072 f
  float* pm2  = pm1 + NS1 * T;              // 131072
  float* pZ   = pm2 + NS1 * T;              // 131072
  int*   pi1  = (int*)(pZ + NS1 * T);       // 131072
  int*   pi2  = pi1 + NS1 * T;              // 131072
  float* avg  = (float*)(pi2 + NS1 * T);    // 16384
  float* scal = avg + 16384;                // 4: sampE, vq, counter, pad
  float* sc2g = scal + 4;                   // 8192

  k_prep<<<161, 256, 0, stream>>>(emb, z, embn, ses2, zf, a02, ehl, zhl,
                                  avg, scal);
  k_pass1<<<dim3(T / 128, NS1), 256, 0, stream>>>(ehl, zhl,
                                                  pm1, pm2, pZ, pi1, pi2);
  k_zm<<<64, 256, 0, stream>>>(pZ, sc2g, pm1, pm2, pi1, pi2, zf, embn,
                               ses2, a02, scal, out);
  k_pass2<<<(N_E / 128) * RS2, 256, 0, stream>>>(ehl, zhl, sc2g, avg,
                                                 scal, out);
}

// Round 10
// 175.297 us; speedup vs baseline: 1.2379x; 1.2379x over previous
//
#include <hip/hip_runtime.h>

// VQ-VAE vector quantize + losses, MI355X.
// T=8192 rows, N_E=16384 codes, D=32.
// R25: R24 post-mortem — pass2's per-block threadfence tail doubled it
//      (1024 device-scope fences; revert to R22's 32-block k_mf tail).
//      pass1 slim epilogue VERIFIED (absmax unchanged) — keep.
//      Key synthesis: pass1 @ VALU 60% vs pass2 (skipped) @ VALU 23%,
//      both ~54us -> pass1 near-VALU-bound, pass2 skeleton latency-bound
//      at 4 waves/SIMD. R25 combines the three verified pieces:
//      - 512-thread blocks: 8 waves x 16 rows sharing R22's 2x16KB
//        staged dbuf; grid stays 1024 = 4 blocks/CU -> 32 waves/CU (max).
//        16-row body = ~46 VGPR (R18-proven) <= 64 -> true 8 waves/SIMD;
//        (512,4) bounds = 128-reg budget (no allocator pressure).
//        Same per-block fixed costs and 256MB L2 traffic as R22.
//      - pass1 tile-skip (mirror of pass2's): skip tail+exp2 when
//        __any(max4(acc) > min4(m1) - 30) fails; skipped keys are >=30
//        below running max -> argmin safe, Z rel err < 1e-6.
//      - pass1 slim epilogue (packed 10-bit (tile<<4)|c keys; shuffle
//        only m1/m2/Zs; decode indices post-reduce).
//      Tripwires: VGPR>64 (occupancy fallback -> flat), WRITE ~2.5MB,
//      absmax 2.44e-4.

#define N_E 16384
#define ED 32
#define T 8192
#define NS1 16      // pass-1 code splits (1024 codes each)
#define RS2 8       // pass-2 row splits  (1024 rows each)
#define SKIPM -36.0f
#define SKIP1 30.0f
#define PHT 8       // tiles per staged phase (16KB)

#define K2 288.53900817779268f      // 200 * log2(e)
#define NS2F -144.26950408889634f   // -100 * log2(e)
#define BIAS1 -208.53900817779268f  // 80 + 2*NS2F
#define SC2C -64.26950408889634f    // 80 + NS2F
#define LN2 0.6931471805599453f

typedef __attribute__((ext_vector_type(8))) short s16x8;
typedef __attribute__((ext_vector_type(4))) float f32x4;

__device__ __forceinline__ float fexp2(float x) { return __builtin_amdgcn_exp2f(x); }
__device__ __forceinline__ float flog2(float x) { return __builtin_amdgcn_logf(x); }
__device__ __forceinline__ float fmed3(float a, float b, float c) {
  return __builtin_amdgcn_fmed3f(a, b, c);
}

// async global->LDS, 16B per lane; LDS dest = wave-uniform base + lane*16.
__device__ __forceinline__ void gload16(const void* g, void* l) {
  __builtin_amdgcn_global_load_lds(
      (const __attribute__((address_space(1))) void*)g,
      (__attribute__((address_space(3))) void*)l, 16, 0, 0);
}

__device__ __forceinline__ unsigned short f2bf(float x) {
  unsigned u = __float_as_uint(x);
  unsigned r = (u + 0x7FFFu + ((u >> 16) & 1u)) >> 16;
  return (unsigned short)r;
}
__device__ __forceinline__ float bf2f(unsigned short h) {
  return __uint_as_float(((unsigned)h) << 16);
}

// exact fp32 dot of a streamed row with 8 resident float4s (by value)
__device__ __forceinline__ float dot32x(const float* __restrict__ p,
    float4 z0, float4 z1, float4 z2, float4 z3,
    float4 z4, float4 z5, float4 z6, float4 z7) {
  const float4* e = (const float4*)p;
  float a0 = 0.f, a1 = 0.f, a2 = 0.f, a3 = 0.f; float4 q;
  q = e[0]; a0 = fmaf(q.x, z0.x, a0); a0 = fmaf(q.y, z0.y, a0);
            a0 = fmaf(q.z, z0.z, a0); a0 = fmaf(q.w, z0.w, a0);
  q = e[1]; a1 = fmaf(q.x, z1.x, a1); a1 = fmaf(q.y, z1.y, a1);
            a1 = fmaf(q.z, z1.z, a1); a1 = fmaf(q.w, z1.w, a1);
  q = e[2]; a2 = fmaf(q.x, z2.x, a2); a2 = fmaf(q.y, z2.y, a2);
            a2 = fmaf(q.z, z2.z, a2); a2 = fmaf(q.w, z2.w, a2);
  q = e[3]; a3 = fmaf(q.x, z3.x, a3); a3 = fmaf(q.y, z3.y, a3);
            a3 = fmaf(q.z, z3.z, a3); a3 = fmaf(q.w, z3.w, a3);
  q = e[4]; a0 = fmaf(q.x, z4.x, a0); a0 = fmaf(q.y, z4.y, a0);
            a0 = fmaf(q.z, z4.z, a0); a0 = fmaf(q.w, z4.w, a0);
  q = e[5]; a1 = fmaf(q.x, z5.x, a1); a1 = fmaf(q.y, z5.y, a1);
            a1 = fmaf(q.z, z5.z, a1); a1 = fmaf(q.w, z5.w, a1);
  q = e[6]; a2 = fmaf(q.x, z6.x, a2); a2 = fmaf(q.y, z6.y, a2);
            a2 = fmaf(q.z, z6.z, a2); a2 = fmaf(q.w, z6.w, a2);
  q = e[7]; a3 = fmaf(q.x, z7.x, a3); a3 = fmaf(q.y, z7.y, a3);
            a3 = fmaf(q.z, z7.z, a3); a3 = fmaf(q.w, z7.w, a3);
  return (a0 + a1) + (a2 + a3);
}

// split 8 floats (scaled by sc) of row `row`, group g into hi/lo bf16 frags,
// stored TILE-MAJOR: dst[tile*128 + g*16 + c] (hi), +64 (lo); s16x8 units.
__device__ __forceinline__ void split_store_t(short* __restrict__ base,
    int row, int g, float4 va, float4 vb, float sc) {
  float f[8] = { va.x * sc, va.y * sc, va.z * sc, va.w * sc,
                 vb.x * sc, vb.y * sc, vb.z * sc, vb.w * sc };
  s16x8 H, L;
#pragma unroll
  for (int e = 0; e < 8; ++e) {
    unsigned short h = f2bf(f[e]);
    H[e] = (short)h;
    L[e] = (short)f2bf(f[e] - bf2f(h));
  }
  s16x8* p = (s16x8*)base;
  const int tile = row >> 4, c = row & 15;
  p[tile * 128 + g * 16 + c] = H;
  p[tile * 128 + 64 + g * 16 + c] = L;
}

// --- prep: blocks 0..63 emb rows; 64..95 z transpose; 96..160 zero avg/scal ---
__global__ __launch_bounds__(256) void k_prep(const float* __restrict__ emb,
    const float* __restrict__ z, float* __restrict__ embn,
    float* __restrict__ ses2, float* __restrict__ zf, float* __restrict__ a02,
    short* __restrict__ ehl, short* __restrict__ zhl, float* __restrict__ avg,
    float* __restrict__ scal) {
  if (blockIdx.x < 64) {
    int n = blockIdx.x * 256 + threadIdx.x;
    const float4* r4 = (const float4*)(emb + (size_t)n * ED);
    float4 v[8]; float s = 0.f;
#pragma unroll
    for (int j = 0; j < 8; ++j) {
      v[j] = r4[j];
      s = fmaf(v[j].x, v[j].x, s); s = fmaf(v[j].y, v[j].y, s);
      s = fmaf(v[j].z, v[j].z, s); s = fmaf(v[j].w, v[j].w, s);
    }
    float inv = 1.0f / fmaxf(sqrtf(s), 1e-12f);
    float s2 = 0.f;
    float4* o4 = (float4*)(embn + (size_t)n * ED);
#pragma unroll
    for (int j = 0; j < 8; ++j) {
      float4 w; w.x = v[j].x * inv; w.y = v[j].y * inv;
      w.z = v[j].z * inv; w.w = v[j].w * inv;
      o4[j] = w; v[j] = w;
      s2 = fmaf(w.x, w.x, s2); s2 = fmaf(w.y, w.y, s2);
      s2 = fmaf(w.z, w.z, s2); s2 = fmaf(w.w, w.w, s2);
    }
    ses2[n] = NS2F * s2;               // true value, for the exact refine
#pragma unroll
    for (int g = 0; g < 4; ++g)
      split_store_t(ehl, n, g, v[2 * g], v[2 * g + 1], 1.0f);
  } else if (blockIdx.x < 96) {
    int t = (blockIdx.x - 64) * 256 + threadIdx.x;
    int b = t >> 8, hw = t & 255;
    const float* base = z + (size_t)b * (ED * 256) + hw;
    float4 v[8]; float s = 0.f;
#pragma unroll
    for (int j = 0; j < 8; ++j) {
      float4 w;
      w.x = base[(4 * j + 0) * 256]; w.y = base[(4 * j + 1) * 256];
      w.z = base[(4 * j + 2) * 256]; w.w = base[(4 * j + 3) * 256];
      v[j] = w;
      s = fmaf(w.x, w.x, s); s = fmaf(w.y, w.y, s);
      s = fmaf(w.z, w.z, s); s = fmaf(w.w, w.w, s);
    }
    float inv = 1.0f / fmaxf(sqrtf(s), 1e-12f);
    float s2 = 0.f;
    float4* o4 = (float4*)(zf + (size_t)t * ED);
#pragma unroll
    for (int j = 0; j < 8; ++j) {
      float4 w; w.x = v[j].x * inv; w.y = v[j].y * inv;
      w.z = v[j].z * inv; w.w = v[j].w * inv;
      o4[j] = w; v[j] = w;
      s2 = fmaf(w.x, w.x, s2); s2 = fmaf(w.y, w.y, s2);
      s2 = fmaf(w.z, w.z, s2); s2 = fmaf(w.w, w.w, s2);
    }
    a02[t] = NS2F * s2;               // only k_mf (exact refine) uses this
#pragma unroll
    for (int g = 0; g < 4; ++g)
      split_store_t(zhl, t, g, v[2 * g], v[2 * g + 1], K2);
  } else if (blockIdx.x < 160) {
    avg[(blockIdx.x - 96) * 256 + threadIdx.x] = 0.f;
  } else {
    if (threadIdx.x < 4) scal[threadIdx.x] = 0.f;  // [0]=sampE [1]=vq [2]=cnt
  }
}

// --- pass 1: block = 512 thr = 8 waves x 16 rows (1 A-pair each), sweeps
//     a 1024-code split (64 tiles, 8 phases x 8). B staged via gload_lds
//     into 2x16KB dbuf shared by 8 waves. Bias = const 80+2*NS2F. Packed
//     keys (tile<<4)|c in 10 mantissa LSBs; tile-skip on
//     __any(max4(acc) > min4(m1)-30). Slim epilogue (m1/m2/Zs only). ---
__global__ __launch_bounds__(512, 4) void k_pass1(
    const short* __restrict__ ehl, const short* __restrict__ zhl,
    float* __restrict__ pm1, float* __restrict__ pm2, float* __restrict__ pZ,
    int* __restrict__ pi1, int* __restrict__ pi2) {
  const int tid = threadIdx.x;
  const int lane = tid & 63, wv = tid >> 6;
  const int q = lane >> 4, c = lane & 15;
  const int rowbase = blockIdx.x * 128 + wv * 16;
  const int nb0 = blockIdx.y * (N_E / NS1);
  const int NT = (N_E / NS1) / 16;  // 64
  const int NP = NT / PHT;          // 8

  __shared__ s16x8 dbuf[2][PHT * 128];   // 2 x 16KB

  const s16x8* zg = (const s16x8*)zhl;
  const int atile = blockIdx.x * 8 + wv;
  s16x8 ah = zg[atile * 128 + lane], al = zg[atile * 128 + 64 + lane];

  f32x4 bias;
#pragma unroll
  for (int r = 0; r < 4; ++r) bias[r] = BIAS1;

  float m1[4], m2[4], Zs[4];
#pragma unroll
  for (int k = 0; k < 4; ++k) { m1[k] = -1e30f; m2[k] = -1e30f; Zs[k] = 0.f; }

  const s16x8* eg = (const s16x8*)ehl + (size_t)(nb0 >> 4) * 128;

  // stage phase 0: 16KB; wave wv covers s16x8 [wv*128, wv*128+128)
  gload16(eg + wv * 128 + lane,      &dbuf[0][wv * 128]);
  gload16(eg + wv * 128 + 64 + lane, &dbuf[0][wv * 128 + 64]);
  __syncthreads();

  for (int p = 0; p < NP; ++p) {
    if (p + 1 < NP) {
      const s16x8* gs = eg + (p + 1) * (PHT * 128);
      s16x8* lb = &dbuf[(p + 1) & 1][0];
      gload16(gs + wv * 128 + lane,      lb + wv * 128);
      gload16(gs + wv * 128 + 64 + lane, lb + wv * 128 + 64);
    }
    const s16x8* bb = &dbuf[p & 1][0];
#pragma unroll
    for (int tt = 0; tt < PHT; ++tt) {
      s16x8 bh = bb[tt * 128 + lane], bl = bb[tt * 128 + 64 + lane];
      const unsigned tuc = (((unsigned)(p * PHT + tt)) << 4) | (unsigned)c;

      f32x4 acc = __builtin_amdgcn_mfma_f32_16x16x32_bf16(ah, bh, bias, 0, 0, 0);
      acc = __builtin_amdgcn_mfma_f32_16x16x32_bf16(al, bh, acc, 0, 0, 0);
      acc = __builtin_amdgcn_mfma_f32_16x16x32_bf16(ah, bl, acc, 0, 0, 0);

      // tile-skip: a skipped key is >=30 below this lane's running max ->
      // cannot be top-1 (bf16-split err << 30) and Z rel err < 1e-6.
      float m4 = fmaxf(fmaxf(acc[0], acc[1]), fmaxf(acc[2], acc[3]));
      float mloc = fminf(fminf(m1[0], m1[1]), fminf(m1[2], m1[3]));
      if (__any(m4 > mloc - SKIP1)) {
#pragma unroll
        for (int r = 0; r < 4; ++r) {
          float fb = acc[r];
          float key = __uint_as_float((__float_as_uint(fb) & 0xFFFFFC00u) | tuc);
          m2[r] = fmed3(key, m1[r], m2[r]);
          m1[r] = fmaxf(m1[r], key);
          Zs[r] += fexp2(fb);
        }
      }
    }
    __syncthreads();
  }

  // 16-lane reduce on packed keys only (indices decoded after)
#pragma unroll
  for (int d = 1; d < 16; d <<= 1) {
#pragma unroll
    for (int k = 0; k < 4; ++k) {
      float o1 = __shfl_xor(m1[k], d);
      float o2 = __shfl_xor(m2[k], d);
      float oZ = __shfl_xor(Zs[k], d);
      float lo = fminf(m1[k], o1);
      m1[k] = fmaxf(m1[k], o1);
      m2[k] = fmaxf(lo, fmaxf(m2[k], o2));
      Zs[k] += oZ;
    }
  }

#pragma unroll
  for (int k = 0; k < 4; ++k) {
    if (c == k) {
      const int t = rowbase + q * 4 + k;
      const int pdx = blockIdx.y * T + t;
      const unsigned k1 = __float_as_uint(m1[k]);
      const unsigned k2 = __float_as_uint(m2[k]);
      pm1[pdx] = m1[k]; pm2[pdx] = m2[k]; pZ[pdx] = Zs[k];
      pi1[pdx] = nb0 + (int)(((k1 >> 4) & 63u) << 4) + (int)(k1 & 15u);
      pi2[pdx] = nb0 + (int)(((k2 >> 4) & 63u) << 4) + (int)(k2 & 15u);
    }
  }
}

// --- zred: per-row Z merge + lse shift (bias-free form), once. ---
__global__ __launch_bounds__(256) void k_zred(const float* __restrict__ pZ,
    float* __restrict__ sc2g) {
  const int t = blockIdx.x * 256 + threadIdx.x;
  float Z = 0.f;
  for (int s = 0; s < NS1; ++s) Z += pZ[s * T + t];
  sc2g[t] = SC2C - flog2(Z);
}

// --- pass 2: block = 512 thr = 8 waves x 16 codes (1 A-pair each), sweeps
//     a 1024-row split. zhl staged (2x16KB dbuf); sc2 (4KB) staged once.
//     Tile-skip: __any(max4(acc)+cc > -36). No fence tail (R24 lesson). ---
__global__ __launch_bounds__(512, 4) void k_pass2(
    const short* __restrict__ ehl, const short* __restrict__ zhl,
    const float* __restrict__ sc2g,
    float* __restrict__ avg, float* __restrict__ scal) {
  const int tid = threadIdx.x;
  const int lane = tid & 63, wv = tid >> 6;
  const int q = lane >> 4, c = lane & 15;
  const int bx = blockIdx.x & 127, by = blockIdx.x >> 7;
  const int tb0 = by * (T / RS2);
  const int cbase = bx * 128 + wv * 16;
  const int NT = (T / RS2) / 16;    // 64
  const int NP = NT / PHT;          // 8

  __shared__ s16x8 dbuf[2][PHT * 128];   // 32KB
  __shared__ float sc2l[T / RS2];        // 1024 f = 4KB

  ((float2*)sc2l)[tid] = ((const float2*)(sc2g + tb0))[tid];

  const s16x8* eg = (const s16x8*)ehl;
  const int atile = bx * 8 + wv;
  s16x8 ah = eg[atile * 128 + lane], al = eg[atile * 128 + 64 + lane];

  f32x4 sg;
#pragma unroll
  for (int r = 0; r < 4; ++r) sg[r] = NS2F;

  float accP[4], accE[4];
#pragma unroll
  for (int k = 0; k < 4; ++k) { accP[k] = 0.f; accE[k] = 0.f; }

  const s16x8* zt = (const s16x8*)zhl + (size_t)(tb0 >> 4) * 128;

  gload16(zt + wv * 128 + lane,      &dbuf[0][wv * 128]);
  gload16(zt + wv * 128 + 64 + lane, &dbuf[0][wv * 128 + 64]);
  __syncthreads();

  for (int p = 0; p < NP; ++p) {
    if (p + 1 < NP) {
      const s16x8* gs = zt + (p + 1) * (PHT * 128);
      s16x8* lb = &dbuf[(p + 1) & 1][0];
      gload16(gs + wv * 128 + lane,      lb + wv * 128);
      gload16(gs + wv * 128 + 64 + lane, lb + wv * 128 + 64);
    }
    const s16x8* bb = &dbuf[p & 1][0];
#pragma unroll
    for (int tt = 0; tt < PHT; ++tt) {
      s16x8 bh = bb[tt * 128 + lane], bl = bb[tt * 128 + 64 + lane];
      float cc = sc2l[(p * PHT + tt) * 16 + c];

      f32x4 acc = __builtin_amdgcn_mfma_f32_16x16x32_bf16(ah, bh, sg, 0, 0, 0);
      acc = __builtin_amdgcn_mfma_f32_16x16x32_bf16(al, bh, acc, 0, 0, 0);
      acc = __builtin_amdgcn_mfma_f32_16x16x32_bf16(ah, bl, acc, 0, 0, 0);

      float m4 = fmaxf(fmaxf(acc[0], acc[1]), fmaxf(acc[2], acc[3]));
      if (__any(m4 + cc > SKIPM)) {
#pragma unroll
        for (int r = 0; r < 4; ++r) {
          float dl = acc[r] + cc;   // fb - lse (<=0)
          float pe = fexp2(dl);     // underflow -> 0
          accP[r] += pe;
          accE[r] = fmaf(pe, dl, accE[r]);
        }
      }
    }
    __syncthreads();
  }

  float etot = 0.f;
#pragma unroll
  for (int k = 0; k < 4; ++k) etot += accE[k];

#pragma unroll
  for (int d = 1; d < 16; d <<= 1) {
#pragma unroll
    for (int k = 0; k < 4; ++k) accP[k] += __shfl_xor(accP[k], d);
  }
#pragma unroll
  for (int k = 0; k < 4; ++k) {
    if (c == k) atomicAdd(&avg[cbase + q * 4 + k], accP[k]);
  }

  float* red = sc2l;                 // sweep done; reuse LDS (post-barrier)
  __syncthreads();
  red[tid] = etot;
  __syncthreads();
  for (int st = 256; st > 0; st >>= 1) {
    if (tid < st) red[tid] += red[tid + st];
    __syncthreads();
  }
  if (tid == 0) atomicAdd(&scal[0], red[0]);
}

// --- merge-final: 32 blocks, thread = row. Top-2 combine, exact fp32
//     refine, vq sum + straight-through output; last block finals
//     (R22's verified tail: 32 fences only). ---
__global__ __launch_bounds__(256) void k_mf(
    const float* __restrict__ pm1, const float* __restrict__ pm2,
    const int* __restrict__ pi1, const int* __restrict__ pi2,
    const float* __restrict__ zf, const float* __restrict__ embn,
    const float* __restrict__ ses2, const float* __restrict__ a02,
    float* __restrict__ avg, float* __restrict__ scal, float* __restrict__ out) {
  const int tid = threadIdx.x;
  const int t = blockIdx.x * 256 + tid;
  __shared__ float red[256];
  __shared__ unsigned sord;

  float m1 = -1e30f, m2 = -1e30f;
  int i1 = 0, i2 = 0;
  for (int s = 0; s < NS1; ++s) {
    const int p = s * T + t;
    float sm1 = pm1[p], sm2 = pm2[p];
    int si1 = pi1[p], si2 = pi2[p];
    bool c1 = sm1 > m1;
    float lm = c1 ? m1 : sm1;
    int li = c1 ? i1 : si1;
    float nm1 = c1 ? sm1 : m1;
    int ni1 = c1 ? si1 : i1;
    bool cb = sm2 > m2;
    float mm2 = cb ? sm2 : m2;
    int mi2 = cb ? si2 : i2;
    bool c3 = mm2 > lm;
    m1 = nm1; i1 = ni1;
    m2 = c3 ? mm2 : lm;
    i2 = c3 ? mi2 : li;
  }
  const float a02t = a02[t];

  const float4* zr4 = (const float4*)(zf + (size_t)t * ED);
  float4 z0 = zr4[0], z1 = zr4[1], z2 = zr4[2], z3 = zr4[3];
  float4 z4 = zr4[4], z5 = zr4[5], z6 = zr4[6], z7 = zr4[7];
  float d1 = dot32x(embn + (size_t)i1 * ED, z0, z1, z2, z3, z4, z5, z6, z7);
  float d2 = dot32x(embn + (size_t)i2 * ED, z0, z1, z2, z3, z4, z5, z6, z7);
  float fb1 = fmaf(K2, d1, a02t + ses2[i1]);   // true a02/ses2: exact rule
  float fb2 = fmaf(K2, d2, a02t + ses2[i2]);
  int bi = (fb2 > fb1 || (fb2 == fb1 && i2 < i1)) ? i2 : i1;

  const int b = t >> 8, hw = t & 255;
  float* ob = out + (size_t)b * (ED * 256) + hw;
  float ss = 0.f;
  const float4* e4 = (const float4*)(embn + (size_t)bi * ED);
#pragma unroll
  for (int j = 0; j < 8; ++j) {
    float4 qv = e4[j];
    float4 zv = (j == 0) ? z0 : (j == 1) ? z1 : (j == 2) ? z2 : (j == 3) ? z3
              : (j == 4) ? z4 : (j == 5) ? z5 : (j == 6) ? z6 : z7;
    float df;
    df = qv.x - zv.x; ss = fmaf(df, df, ss); ob[(4 * j + 0) * 256] = zv.x + (qv.x - zv.x);
    df = qv.y - zv.y; ss = fmaf(df, df, ss); ob[(4 * j + 1) * 256] = zv.y + (qv.y - zv.y);
    df = qv.z - zv.z; ss = fmaf(df, df, ss); ob[(4 * j + 2) * 256] = zv.z + (qv.z - zv.z);
    df = qv.w - zv.w; ss = fmaf(df, df, ss); ob[(4 * j + 3) * 256] = zv.w + (qv.w - zv.w);
  }
  red[tid] = ss;
  __syncthreads();
  for (int st = 128; st > 0; st >>= 1) {
    if (tid < st) red[tid] += red[tid + st];
    __syncthreads();
  }
  if (tid == 0) atomicAdd(&scal[1], red[0]);

  // last-block final (avg/scal[0] were completed by the previous kernel)
  __threadfence();
  __syncthreads();
  if (tid == 0) sord = atomicAdd((unsigned*)&scal[2], 1u);
  __syncthreads();
  if (sord == 31) {
    float s = 0.f;
    for (int i = tid; i < N_E; i += 256) {
      float a = avg[i] * (1.0f / T);
      s += a * (flog2(a + 1e-5f) * LN2);
    }
    red[tid] = s;
    __syncthreads();
    for (int st = 128; st > 0; st >>= 1) {
      if (tid < st) red[tid] += red[tid + st];
      __syncthreads();
    }
    if (tid == 0) {
      float avg_entropy = -red[0];
      float se = scal[0];
      float vqs = __hip_atomic_load(&scal[1], __ATOMIC_RELAXED,
                                    __HIP_MEMORY_SCOPE_AGENT);
      float sample_entropy = -(se * LN2) * (1.0f / T);
      float vq = vqs * (1.0f / (T * ED));
      out[T * ED + 0] = vq;
      out[T * ED + 1] = 0.25f * vq;
      out[T * ED + 2] = 0.1f * (sample_entropy - avg_entropy);
    }
  }
}

extern "C" void kernel_launch(void* const* d_in, const int* in_sizes, int n_in,
                              void* d_out, int out_size, void* d_ws, size_t ws_size,
                              hipStream_t stream) {
  const float* z = (const float*)d_in[0];
  const float* emb = (const float*)d_in[1];
  float* out = (float*)d_out;
  float* w = (float*)d_ws;

  float* embn = w;                          // 524288 f
  float* ses2 = embn + 524288;              // 16384
  float* zf   = ses2 + 16384;               // 262144
  float* a02  = zf + 262144;                // 8192
  short* ehl  = (short*)(a02 + 8192);       // 1048576 sh (524288 f)
  short* zhl  = ehl + 1048576;              // 524288 sh  (262144 f)
  float* pm1  = (float*)(zhl + 524288);     // NS1*T = 131072 f
  float* pm2  = pm1 + NS1 * T;              // 131072
  float* pZ   = pm2 + NS1 * T;              // 131072
  int*   pi1  = (int*)(pZ + NS1 * T);       // 131072
  int*   pi2  = pi1 + NS1 * T;              // 131072
  float* avg  = (float*)(pi2 + NS1 * T);    // 16384
  float* scal = avg + 16384;                // 4: sampE, vq, counter, pad
  float* sc2g = scal + 4;                   // 8192

  k_prep<<<161, 256, 0, stream>>>(emb, z, embn, ses2, zf, a02, ehl, zhl,
                                  avg, scal);
  k_pass1<<<dim3(T / 128, NS1), 512, 0, stream>>>(ehl, zhl,
                                                  pm1, pm2, pZ, pi1, pi2);
  k_zred<<<T / 256, 256, 0, stream>>>(pZ, sc2g);
  k_pass2<<<(N_E / 128) * RS2, 512, 0, stream>>>(ehl, zhl, sc2g, avg, scal);
  k_mf<<<32, 256, 0, stream>>>(pm1, pm2, pi1, pi2, zf, embn, ses2, a02,
                               avg, scal, out);
}

// Round 11
// 155.927 us; speedup vs baseline: 1.3917x; 1.1242x over previous
//
#include <hip/hip_runtime.h>

// VQ-VAE vector quantize + losses, MI355X.
// T=8192 rows, N_E=16384 codes, D=32.
// R26: 11-round synthesis — sweeps are ISSUE-bound (duration tracks total
//      instruction count; occupancy 28->57% and L2 traffic 8x cut both
//      null; MfmaUtil+VALU+trans+LDS ~ issue saturation; 3ms gaps between
//      54us bursts keep DVFS clocks low). Only lever left: total work.
//      TEMP=0.01 => softmax is ~1-sparse (top-2 is ~13 log2 below top-1).
//      Pass2's 134M-element sweep is determined by ~8 elements/row within
//      33 log2 of the row max — and pass1's per-lane m1/m2 keys (top-2 of
//      disjoint 64-elem buckets, 512 keys/row) already contain them:
//      true top-1 always; contributors missed only if 3+ share a bucket
//      (P~1e-3/row, error ~1e-6). Z stays EXACT via pZ. So:
//      - k_pass1: R22 geometry (verified 53.8us) + R24 packed keys
//        (verified); epilogue stores per-lane m1/m2 keys to cand1/cand2
//        (f32x4 each) + Zs-only shuffle reduce -> pZ. No pm/pi arrays.
//      - k_fin (NEW, replaces pass2+zred+mf): 256 blocks, 8 lanes/row:
//        lse from pZ, scan 512 keys, p=exp2(midband(key)-lZ) for
//        dl>-36 -> avg atomics + sampE; top-2(+slot) merge -> exact
//        refine -> output + vq. ~2M ops vs 134M.
//      - k_last: 1 block, final scalars. Kernel boundaries = ordering;
//        NO fences/counters (R24 lesson).
//      Tripwires: absmax > 2.5e-4 => quantized-p path failed (revert);
//      pass1 WRITE ~18MB is EXPECTED (cand arrays), VGPR>64 = spill.

#define N_E 16384
#define ED 32
#define T 8192
#define NS1 16      // pass-1 code splits (1024 codes each)
#define SKIPM -36.0f
#define PHT 8       // tiles per staged phase (16KB)

#define K2 288.53900817779268f      // 200 * log2(e)
#define NS2F -144.26950408889634f   // -100 * log2(e)
#define BIAS1 -208.53900817779268f  // 80 + 2*NS2F
#define LN2 0.6931471805599453f

typedef __attribute__((ext_vector_type(8))) short s16x8;
typedef __attribute__((ext_vector_type(4))) float f32x4;

__device__ __forceinline__ float fexp2(float x) { return __builtin_amdgcn_exp2f(x); }
__device__ __forceinline__ float flog2(float x) { return __builtin_amdgcn_logf(x); }
__device__ __forceinline__ float fmed3(float a, float b, float c) {
  return __builtin_amdgcn_fmed3f(a, b, c);
}

// async global->LDS, 16B per lane; LDS dest = wave-uniform base + lane*16.
__device__ __forceinline__ void gload16(const void* g, void* l) {
  __builtin_amdgcn_global_load_lds(
      (const __attribute__((address_space(1))) void*)g,
      (__attribute__((address_space(3))) void*)l, 16, 0, 0);
}

__device__ __forceinline__ unsigned short f2bf(float x) {
  unsigned u = __float_as_uint(x);
  unsigned r = (u + 0x7FFFu + ((u >> 16) & 1u)) >> 16;
  return (unsigned short)r;
}
__device__ __forceinline__ float bf2f(unsigned short h) {
  return __uint_as_float(((unsigned)h) << 16);
}

// exact fp32 dot of a streamed row with 8 resident float4s (by value)
__device__ __forceinline__ float dot32x(const float* __restrict__ p,
    float4 z0, float4 z1, float4 z2, float4 z3,
    float4 z4, float4 z5, float4 z6, float4 z7) {
  const float4* e = (const float4*)p;
  float a0 = 0.f, a1 = 0.f, a2 = 0.f, a3 = 0.f; float4 q;
  q = e[0]; a0 = fmaf(q.x, z0.x, a0); a0 = fmaf(q.y, z0.y, a0);
            a0 = fmaf(q.z, z0.z, a0); a0 = fmaf(q.w, z0.w, a0);
  q = e[1]; a1 = fmaf(q.x, z1.x, a1); a1 = fmaf(q.y, z1.y, a1);
            a1 = fmaf(q.z, z1.z, a1); a1 = fmaf(q.w, z1.w, a1);
  q = e[2]; a2 = fmaf(q.x, z2.x, a2); a2 = fmaf(q.y, z2.y, a2);
            a2 = fmaf(q.z, z2.z, a2); a2 = fmaf(q.w, z2.w, a2);
  q = e[3]; a3 = fmaf(q.x, z3.x, a3); a3 = fmaf(q.y, z3.y, a3);
            a3 = fmaf(q.z, z3.z, a3); a3 = fmaf(q.w, z3.w, a3);
  q = e[4]; a0 = fmaf(q.x, z4.x, a0); a0 = fmaf(q.y, z4.y, a0);
            a0 = fmaf(q.z, z4.z, a0); a0 = fmaf(q.w, z4.w, a0);
  q = e[5]; a1 = fmaf(q.x, z5.x, a1); a1 = fmaf(q.y, z5.y, a1);
            a1 = fmaf(q.z, z5.z, a1); a1 = fmaf(q.w, z5.w, a1);
  q = e[6]; a2 = fmaf(q.x, z6.x, a2); a2 = fmaf(q.y, z6.y, a2);
            a2 = fmaf(q.z, z6.z, a2); a2 = fmaf(q.w, z6.w, a2);
  q = e[7]; a3 = fmaf(q.x, z7.x, a3); a3 = fmaf(q.y, z7.y, a3);
            a3 = fmaf(q.z, z7.z, a3); a3 = fmaf(q.w, z7.w, a3);
  return (a0 + a1) + (a2 + a3);
}

// split 8 floats (scaled by sc) of row `row`, group g into hi/lo bf16 frags,
// stored TILE-MAJOR: dst[tile*128 + g*16 + c] (hi), +64 (lo); s16x8 units.
__device__ __forceinline__ void split_store_t(short* __restrict__ base,
    int row, int g, float4 va, float4 vb, float sc) {
  float f[8] = { va.x * sc, va.y * sc, va.z * sc, va.w * sc,
                 vb.x * sc, vb.y * sc, vb.z * sc, vb.w * sc };
  s16x8 H, L;
#pragma unroll
  for (int e = 0; e < 8; ++e) {
    unsigned short h = f2bf(f[e]);
    H[e] = (short)h;
    L[e] = (short)f2bf(f[e] - bf2f(h));
  }
  s16x8* p = (s16x8*)base;
  const int tile = row >> 4, c = row & 15;
  p[tile * 128 + g * 16 + c] = H;
  p[tile * 128 + 64 + g * 16 + c] = L;
}

// --- prep: blocks 0..63 emb rows; 64..95 z transpose; 96..160 zero avg/scal ---
__global__ __launch_bounds__(256) void k_prep(const float* __restrict__ emb,
    const float* __restrict__ z, float* __restrict__ embn,
    float* __restrict__ ses2, float* __restrict__ zf, float* __restrict__ a02,
    short* __restrict__ ehl, short* __restrict__ zhl, float* __restrict__ avg,
    float* __restrict__ scal) {
  if (blockIdx.x < 64) {
    int n = blockIdx.x * 256 + threadIdx.x;
    const float4* r4 = (const float4*)(emb + (size_t)n * ED);
    float4 v[8]; float s = 0.f;
#pragma unroll
    for (int j = 0; j < 8; ++j) {
      v[j] = r4[j];
      s = fmaf(v[j].x, v[j].x, s); s = fmaf(v[j].y, v[j].y, s);
      s = fmaf(v[j].z, v[j].z, s); s = fmaf(v[j].w, v[j].w, s);
    }
    float inv = 1.0f / fmaxf(sqrtf(s), 1e-12f);
    float s2 = 0.f;
    float4* o4 = (float4*)(embn + (size_t)n * ED);
#pragma unroll
    for (int j = 0; j < 8; ++j) {
      float4 w; w.x = v[j].x * inv; w.y = v[j].y * inv;
      w.z = v[j].z * inv; w.w = v[j].w * inv;
      o4[j] = w; v[j] = w;
      s2 = fmaf(w.x, w.x, s2); s2 = fmaf(w.y, w.y, s2);
      s2 = fmaf(w.z, w.z, s2); s2 = fmaf(w.w, w.w, s2);
    }
    ses2[n] = NS2F * s2;               // true value, for the exact refine
#pragma unroll
    for (int g = 0; g < 4; ++g)
      split_store_t(ehl, n, g, v[2 * g], v[2 * g + 1], 1.0f);
  } else if (blockIdx.x < 96) {
    int t = (blockIdx.x - 64) * 256 + threadIdx.x;
    int b = t >> 8, hw = t & 255;
    const float* base = z + (size_t)b * (ED * 256) + hw;
    float4 v[8]; float s = 0.f;
#pragma unroll
    for (int j = 0; j < 8; ++j) {
      float4 w;
      w.x = base[(4 * j + 0) * 256]; w.y = base[(4 * j + 1) * 256];
      w.z = base[(4 * j + 2) * 256]; w.w = base[(4 * j + 3) * 256];
      v[j] = w;
      s = fmaf(w.x, w.x, s); s = fmaf(w.y, w.y, s);
      s = fmaf(w.z, w.z, s); s = fmaf(w.w, w.w, s);
    }
    float inv = 1.0f / fmaxf(sqrtf(s), 1e-12f);
    float s2 = 0.f;
    float4* o4 = (float4*)(zf + (size_t)t * ED);
#pragma unroll
    for (int j = 0; j < 8; ++j) {
      float4 w; w.x = v[j].x * inv; w.y = v[j].y * inv;
      w.z = v[j].z * inv; w.w = v[j].w * inv;
      o4[j] = w; v[j] = w;
      s2 = fmaf(w.x, w.x, s2); s2 = fmaf(w.y, w.y, s2);
      s2 = fmaf(w.z, w.z, s2); s2 = fmaf(w.w, w.w, s2);
    }
    a02[t] = NS2F * s2;               // only k_fin (exact refine) uses this
#pragma unroll
    for (int g = 0; g < 4; ++g)
      split_store_t(zhl, t, g, v[2 * g], v[2 * g + 1], K2);
  } else if (blockIdx.x < 160) {
    avg[(blockIdx.x - 96) * 256 + threadIdx.x] = 0.f;
  } else {
    if (threadIdx.x < 4) scal[threadIdx.x] = 0.f;  // [0]=sampE [1]=vq
  }
}

// --- pass 1: R22 geometry (block = 128 rows, 4 waves x 32 = 2 A-pairs),
//     sweeps a 1024-code split (64 tiles, 8 phases x 8), gload_lds 2x16KB
//     dbuf, const bias. Packed keys (tile<<4)|c in 10 mantissa LSBs.
//     Epilogue: Zs-only 16-lane reduce -> pZ; per-lane m1/m2 keys stored
//     to cand1/cand2 (bucket-top-2 candidate sets, 512 keys/row). ---
__global__ __launch_bounds__(256, 4) void k_pass1(
    const short* __restrict__ ehl, const short* __restrict__ zhl,
    float* __restrict__ pZ, float* __restrict__ cand1,
    float* __restrict__ cand2) {
  const int tid = threadIdx.x;
  const int lane = tid & 63, wv = tid >> 6;
  const int q = lane >> 4, c = lane & 15;
  const int rowbase = blockIdx.x * 128 + wv * 32;
  const int nb0 = blockIdx.y * (N_E / NS1);
  const int NT = (N_E / NS1) / 16;  // 64
  const int NP = NT / PHT;          // 8

  __shared__ s16x8 dbuf[2][PHT * 128];   // 2 x 16KB

  const s16x8* zg = (const s16x8*)zhl;
  const int atile = rowbase >> 4;
  s16x8 ah[2], al[2];
#pragma unroll
  for (int rg = 0; rg < 2; ++rg) {
    ah[rg] = zg[(atile + rg) * 128 + lane];
    al[rg] = zg[(atile + rg) * 128 + 64 + lane];
  }

  f32x4 bias;
#pragma unroll
  for (int r = 0; r < 4; ++r) bias[r] = BIAS1;

  float m1[2][4], m2[2][4], Zs[2][4];
#pragma unroll
  for (int rg = 0; rg < 2; ++rg)
#pragma unroll
    for (int k = 0; k < 4; ++k) {
      m1[rg][k] = -1e30f; m2[rg][k] = -1e30f; Zs[rg][k] = 0.f;
    }

  const s16x8* eg = (const s16x8*)ehl + (size_t)(nb0 >> 4) * 128;

  // stage phase 0: 16KB; wave wv covers s16x8 [wv*256, wv*256+256)
#pragma unroll
  for (int j = 0; j < 4; ++j)
    gload16(eg + wv * 256 + j * 64 + lane, &dbuf[0][wv * 256 + j * 64]);
  __syncthreads();

  for (int p = 0; p < NP; ++p) {
    if (p + 1 < NP) {
      const s16x8* gs = eg + (p + 1) * (PHT * 128);
      s16x8* lb = &dbuf[(p + 1) & 1][0];
#pragma unroll
      for (int j = 0; j < 4; ++j)
        gload16(gs + wv * 256 + j * 64 + lane, lb + wv * 256 + j * 64);
    }
    const s16x8* bb = &dbuf[p & 1][0];
#pragma unroll
    for (int tt = 0; tt < PHT; ++tt) {
      s16x8 bh = bb[tt * 128 + lane], bl = bb[tt * 128 + 64 + lane];
      const unsigned tuc = (((unsigned)(p * PHT + tt)) << 4) | (unsigned)c;
#pragma unroll
      for (int rg = 0; rg < 2; ++rg) {
        f32x4 acc = __builtin_amdgcn_mfma_f32_16x16x32_bf16(ah[rg], bh, bias, 0, 0, 0);
        acc = __builtin_amdgcn_mfma_f32_16x16x32_bf16(al[rg], bh, acc, 0, 0, 0);
        acc = __builtin_amdgcn_mfma_f32_16x16x32_bf16(ah[rg], bl, acc, 0, 0, 0);
#pragma unroll
        for (int r = 0; r < 4; ++r) {
          float fb = acc[r];
          float key = __uint_as_float((__float_as_uint(fb) & 0xFFFFFC00u) | tuc);
          m2[rg][r] = fmed3(key, m1[rg][r], m2[rg][r]);
          m1[rg][r] = fmaxf(m1[rg][r], key);
          Zs[rg][r] += fexp2(fb);
        }
      }
    }
    __syncthreads();
  }

  // Zs-only 16-lane reduce (exact row Z per split)
#pragma unroll
  for (int d = 1; d < 16; d <<= 1) {
#pragma unroll
    for (int rg = 0; rg < 2; ++rg)
#pragma unroll
      for (int k = 0; k < 4; ++k) Zs[rg][k] += __shfl_xor(Zs[rg][k], d);
  }

  const int s = blockIdx.y;
#pragma unroll
  for (int rg = 0; rg < 2; ++rg) {
    float4 v1 = make_float4(m1[rg][0], m1[rg][1], m1[rg][2], m1[rg][3]);
    float4 v2 = make_float4(m2[rg][0], m2[rg][1], m2[rg][2], m2[rg][3]);
    const size_t base = (size_t)(s * 16 + c) * T + (rowbase + rg * 16 + q * 4);
    *(float4*)(cand1 + base) = v1;
    *(float4*)(cand2 + base) = v2;
  }
#pragma unroll
  for (int rg = 0; rg < 2; ++rg)
#pragma unroll
    for (int k = 0; k < 4; ++k)
      if (c == k) pZ[s * T + rowbase + rg * 16 + q * 4 + k] = Zs[rg][k];
}

// --- fin: 256 blocks x 256 thr; 32 rows/block x 8 lanes. Per row: exact
//     lse from pZ; scan 512 candidate keys; p = exp2(midband(key) - lZ)
//     for dl > -36 -> avg atomics + sampE; top-2(+slot) -> exact refine
//     -> straight-through output + vq partial. ---
__global__ __launch_bounds__(256) void k_fin(
    const float* __restrict__ cand1, const float* __restrict__ cand2,
    const float* __restrict__ pZ, const float* __restrict__ zf,
    const float* __restrict__ embn, const float* __restrict__ ses2,
    const float* __restrict__ a02, float* __restrict__ avg,
    float* __restrict__ scal, float* __restrict__ out) {
  const int tid = threadIdx.x;
  const int r = tid & 31, j8 = tid >> 5;
  const int row = blockIdx.x * 32 + r;
  __shared__ float rk1[256], rk2[256], rsE[256];
  __shared__ int ru1[256], ru2[256];
  __shared__ float rvq[32];

  // exact lse: Z = sum of 16 split-partials
  rsE[tid] = pZ[(j8 * 2) * T + row] + pZ[(j8 * 2 + 1) * T + row];
  __syncthreads();
  for (int st = 4; st > 0; st >>= 1) {
    if (j8 < st) rsE[tid] += rsE[tid + 32 * st];
    __syncthreads();
  }
  const float lZ = flog2(rsE[r]);
  __syncthreads();

  float k1 = -1e30f, k2 = -1e30f, sE = 0.f;
  int u1 = 0, u2 = 0;
  for (int m = 0; m < 32; ++m) {
    const int u = j8 * 32 + m;
    const float ca = cand1[(size_t)u * T + row];
    const float cb = cand2[(size_t)u * T + row];
    if (ca > k1) { k2 = k1; u2 = u1; k1 = ca; u1 = u; }
    else if (ca > k2) { k2 = ca; u2 = u; }
    if (cb > k1) { k2 = k1; u2 = u1; k1 = cb; u1 = u; }
    else if (cb > k2) { k2 = cb; u2 = u; }
    // prob path: mid-band corrected fb (id bits replaced by 512)
    const float fa = __uint_as_float((__float_as_uint(ca) & 0xFFFFFC00u) | 512u);
    const float fbv = __uint_as_float((__float_as_uint(cb) & 0xFFFFFC00u) | 512u);
    const float da = fa - lZ, db = fbv - lZ;
    if (da > SKIPM) {
      const float p = fexp2(da); sE = fmaf(p, da, sE);
      const unsigned kid = __float_as_uint(ca) & 1023u;
      atomicAdd(&avg[(u >> 4) * 1024 + (int)((kid >> 4) << 4) + (int)(kid & 15u)], p);
    }
    if (db > SKIPM) {
      const float p = fexp2(db); sE = fmaf(p, db, sE);
      const unsigned kid = __float_as_uint(cb) & 1023u;
      atomicAdd(&avg[(u >> 4) * 1024 + (int)((kid >> 4) << 4) + (int)(kid & 15u)], p);
    }
  }
  rk1[tid] = k1; rk2[tid] = k2; ru1[tid] = u1; ru2[tid] = u2; rsE[tid] = sE;
  __syncthreads();
  for (int st = 4; st > 0; st >>= 1) {
    if (j8 < st) {
      const int o = tid + 32 * st;
      const float ok1 = rk1[o], ok2 = rk2[o];
      const int ou1 = ru1[o], ou2 = ru2[o];
      const float a1v = rk1[tid], a2v = rk2[tid];
      const int b1 = ru1[tid], b2 = ru2[tid];
      if (a1v >= ok1) {
        rk1[tid] = a1v; ru1[tid] = b1;
        if (a2v >= ok1) { rk2[tid] = a2v; ru2[tid] = b2; }
        else            { rk2[tid] = ok1; ru2[tid] = ou1; }
      } else {
        rk1[tid] = ok1; ru1[tid] = ou1;
        if (ok2 >= a1v) { rk2[tid] = ok2; ru2[tid] = ou2; }
        else            { rk2[tid] = a1v; ru2[tid] = b1; }
      }
      rsE[tid] += rsE[o];
    }
    __syncthreads();
  }

  if (j8 == 0) {
    // decode top-2 candidate codes
    const unsigned kk1 = __float_as_uint(rk1[r]) & 1023u;
    const unsigned kk2 = __float_as_uint(rk2[r]) & 1023u;
    const int i1 = (ru1[r] >> 4) * 1024 + (int)((kk1 >> 4) << 4) + (int)(kk1 & 15u);
    const int i2 = (ru2[r] >> 4) * 1024 + (int)((kk2 >> 4) << 4) + (int)(kk2 & 15u);
    const float a02t = a02[row];

    const float4* zr4 = (const float4*)(zf + (size_t)row * ED);
    float4 z0 = zr4[0], z1 = zr4[1], z2 = zr4[2], z3 = zr4[3];
    float4 z4 = zr4[4], z5 = zr4[5], z6 = zr4[6], z7 = zr4[7];
    float d1 = dot32x(embn + (size_t)i1 * ED, z0, z1, z2, z3, z4, z5, z6, z7);
    float d2 = dot32x(embn + (size_t)i2 * ED, z0, z1, z2, z3, z4, z5, z6, z7);
    float fb1 = fmaf(K2, d1, a02t + ses2[i1]);   // exact re-rank
    float fb2 = fmaf(K2, d2, a02t + ses2[i2]);
    int bi = (fb2 > fb1 || (fb2 == fb1 && i2 < i1)) ? i2 : i1;

    const int b = row >> 8, hw = row & 255;
    float* ob = out + (size_t)b * (ED * 256) + hw;
    float ss = 0.f;
    const float4* e4 = (const float4*)(embn + (size_t)bi * ED);
#pragma unroll
    for (int j = 0; j < 8; ++j) {
      float4 qv = e4[j];
      float4 zv = (j == 0) ? z0 : (j == 1) ? z1 : (j == 2) ? z2 : (j == 3) ? z3
                : (j == 4) ? z4 : (j == 5) ? z5 : (j == 6) ? z6 : z7;
      float df;
      df = qv.x - zv.x; ss = fmaf(df, df, ss); ob[(4 * j + 0) * 256] = zv.x + (qv.x - zv.x);
      df = qv.y - zv.y; ss = fmaf(df, df, ss); ob[(4 * j + 1) * 256] = zv.y + (qv.y - zv.y);
      df = qv.z - zv.z; ss = fmaf(df, df, ss); ob[(4 * j + 2) * 256] = zv.z + (qv.z - zv.z);
      df = qv.w - zv.w; ss = fmaf(df, df, ss); ob[(4 * j + 3) * 256] = zv.w + (qv.w - zv.w);
    }
    rvq[r] = ss;
  }
  __syncthreads();
  if (tid == 0) {
    float se = 0.f, vq = 0.f;
    for (int i = 0; i < 32; ++i) { se += rsE[i]; vq += rvq[i]; }
    atomicAdd(&scal[0], se);
    atomicAdd(&scal[1], vq);
  }
}

// --- last: 1 block; avg_entropy + final scalars. Stream order after k_fin
//     is the global barrier (no fences/counters). ---
__global__ __launch_bounds__(256) void k_last(const float* __restrict__ avg,
    const float* __restrict__ scal, float* __restrict__ out) {
  const int tid = threadIdx.x;
  __shared__ float red[256];
  float s = 0.f;
  for (int i = tid; i < N_E; i += 256) {
    float a = avg[i] * (1.0f / T);
    s += a * (flog2(a + 1e-5f) * LN2);
  }
  red[tid] = s;
  __syncthreads();
  for (int st = 128; st > 0; st >>= 1) {
    if (tid < st) red[tid] += red[tid + st];
    __syncthreads();
  }
  if (tid == 0) {
    float avg_entropy = -red[0];
    float sample_entropy = -(scal[0] * LN2) * (1.0f / T);
    float vq = scal[1] * (1.0f / (T * ED));
    out[T * ED + 0] = vq;
    out[T * ED + 1] = 0.25f * vq;
    out[T * ED + 2] = 0.1f * (sample_entropy - avg_entropy);
  }
}

extern "C" void kernel_launch(void* const* d_in, const int* in_sizes, int n_in,
                              void* d_out, int out_size, void* d_ws, size_t ws_size,
                              hipStream_t stream) {
  const float* z = (const float*)d_in[0];
  const float* emb = (const float*)d_in[1];
  float* out = (float*)d_out;
  float* w = (float*)d_ws;

  float* embn = w;                          // 524288 f
  float* ses2 = embn + 524288;              // 16384
  float* zf   = ses2 + 16384;               // 262144
  float* a02  = zf + 262144;                // 8192
  short* ehl  = (short*)(a02 + 8192);       // 1048576 sh (524288 f)
  short* zhl  = ehl + 1048576;              // 524288 sh  (262144 f)
  float* pZ   = (float*)(zhl + 524288);     // NS1*T = 131072 f
  float* cand1 = pZ + NS1 * T;              // 256*T = 2097152 f
  float* cand2 = cand1 + 256 * T;           // 2097152 f
  float* avg  = cand2 + 256 * T;            // 16384
  float* scal = avg + 16384;                // 4: sampE, vq, pad, pad

  k_prep<<<161, 256, 0, stream>>>(emb, z, embn, ses2, zf, a02, ehl, zhl,
                                  avg, scal);
  k_pass1<<<dim3(T / 128, NS1), 256, 0, stream>>>(ehl, zhl, pZ, cand1, cand2);
  k_fin<<<T / 32, 256, 0, stream>>>(cand1, cand2, pZ, zf, embn, ses2, a02,
                                    avg, scal, out);
  k_last<<<1, 256, 0, stream>>>(avg, scal, out);
}

// Round 12
// 145.594 us; speedup vs baseline: 1.4904x; 1.0710x over previous
//
#include <hip/hip_runtime.h>

// VQ-VAE vector quantize + losses, MI355X.
// T=8192 rows, N_E=16384 codes, D=32.
// R27: R26 verified the candidate-set sparse-softmax (155.9us, absmax
//      unchanged). Two cuts this round:
//      - pass1: drop Zs/pZ entirely. The 8x v_exp_f32/tile on the
//        quarter-rate trans pipe was the issue-bound hog; Z is computable
//        from the candidate keys (non-candidates are >=36 log2 below max
//        -> <2e-7 relative, same validated argument as R26's avg_probs).
//        Epilogue is now 2 plain float4 stores (no shuffles at all).
//      - k_fin rebuilt for occupancy: 512 blocks x (16 rows x 16 lanes),
//        32 keys/thread in REGISTERS (unrolled, rule #20); scan1 = top-2
//        + Z + S2 (entropy = S2/Z - lZ closed form); LDS reduce; scan2 =
//        rare dl>-36 avg atomics only. R26's was 256 blocks = 1 block/CU
//        latency-bound.
//      Tripwires: absmax > 2.5e-4 -> Z-from-candidates failed (revert to
//      pZ); pass1 VGPR > 64 = spill; pass1 WRITE ~16.9MB expected.

#define N_E 16384
#define ED 32
#define T 8192
#define NS1 16      // pass-1 code splits (1024 codes each)
#define SKIPM -36.0f
#define PHT 8       // tiles per staged phase (16KB)

#define K2 288.53900817779268f      // 200 * log2(e)
#define NS2F -144.26950408889634f   // -100 * log2(e)
#define BIAS1 -208.53900817779268f  // 80 + 2*NS2F
#define LN2 0.6931471805599453f

typedef __attribute__((ext_vector_type(8))) short s16x8;
typedef __attribute__((ext_vector_type(4))) float f32x4;

__device__ __forceinline__ float fexp2(float x) { return __builtin_amdgcn_exp2f(x); }
__device__ __forceinline__ float flog2(float x) { return __builtin_amdgcn_logf(x); }
__device__ __forceinline__ float fmed3(float a, float b, float c) {
  return __builtin_amdgcn_fmed3f(a, b, c);
}

// mid-band corrected fb from a packed key (id bits replaced by 512)
__device__ __forceinline__ float midband(float key) {
  return __uint_as_float((__float_as_uint(key) & 0xFFFFFC00u) | 512u);
}

// async global->LDS, 16B per lane; LDS dest = wave-uniform base + lane*16.
__device__ __forceinline__ void gload16(const void* g, void* l) {
  __builtin_amdgcn_global_load_lds(
      (const __attribute__((address_space(1))) void*)g,
      (__attribute__((address_space(3))) void*)l, 16, 0, 0);
}

__device__ __forceinline__ unsigned short f2bf(float x) {
  unsigned u = __float_as_uint(x);
  unsigned r = (u + 0x7FFFu + ((u >> 16) & 1u)) >> 16;
  return (unsigned short)r;
}
__device__ __forceinline__ float bf2f(unsigned short h) {
  return __uint_as_float(((unsigned)h) << 16);
}

// exact fp32 dot of a streamed row with 8 resident float4s (by value)
__device__ __forceinline__ float dot32x(const float* __restrict__ p,
    float4 z0, float4 z1, float4 z2, float4 z3,
    float4 z4, float4 z5, float4 z6, float4 z7) {
  const float4* e = (const float4*)p;
  float a0 = 0.f, a1 = 0.f, a2 = 0.f, a3 = 0.f; float4 q;
  q = e[0]; a0 = fmaf(q.x, z0.x, a0); a0 = fmaf(q.y, z0.y, a0);
            a0 = fmaf(q.z, z0.z, a0); a0 = fmaf(q.w, z0.w, a0);
  q = e[1]; a1 = fmaf(q.x, z1.x, a1); a1 = fmaf(q.y, z1.y, a1);
            a1 = fmaf(q.z, z1.z, a1); a1 = fmaf(q.w, z1.w, a1);
  q = e[2]; a2 = fmaf(q.x, z2.x, a2); a2 = fmaf(q.y, z2.y, a2);
            a2 = fmaf(q.z, z2.z, a2); a2 = fmaf(q.w, z2.w, a2);
  q = e[3]; a3 = fmaf(q.x, z3.x, a3); a3 = fmaf(q.y, z3.y, a3);
            a3 = fmaf(q.z, z3.z, a3); a3 = fmaf(q.w, z3.w, a3);
  q = e[4]; a0 = fmaf(q.x, z4.x, a0); a0 = fmaf(q.y, z4.y, a0);
            a0 = fmaf(q.z, z4.z, a0); a0 = fmaf(q.w, z4.w, a0);
  q = e[5]; a1 = fmaf(q.x, z5.x, a1); a1 = fmaf(q.y, z5.y, a1);
            a1 = fmaf(q.z, z5.z, a1); a1 = fmaf(q.w, z5.w, a1);
  q = e[6]; a2 = fmaf(q.x, z6.x, a2); a2 = fmaf(q.y, z6.y, a2);
            a2 = fmaf(q.z, z6.z, a2); a2 = fmaf(q.w, z6.w, a2);
  q = e[7]; a3 = fmaf(q.x, z7.x, a3); a3 = fmaf(q.y, z7.y, a3);
            a3 = fmaf(q.z, z7.z, a3); a3 = fmaf(q.w, z7.w, a3);
  return (a0 + a1) + (a2 + a3);
}

// split 8 floats (scaled by sc) of row `row`, group g into hi/lo bf16 frags,
// stored TILE-MAJOR: dst[tile*128 + g*16 + c] (hi), +64 (lo); s16x8 units.
__device__ __forceinline__ void split_store_t(short* __restrict__ base,
    int row, int g, float4 va, float4 vb, float sc) {
  float f[8] = { va.x * sc, va.y * sc, va.z * sc, va.w * sc,
                 vb.x * sc, vb.y * sc, vb.z * sc, vb.w * sc };
  s16x8 H, L;
#pragma unroll
  for (int e = 0; e < 8; ++e) {
    unsigned short h = f2bf(f[e]);
    H[e] = (short)h;
    L[e] = (short)f2bf(f[e] - bf2f(h));
  }
  s16x8* p = (s16x8*)base;
  const int tile = row >> 4, c = row & 15;
  p[tile * 128 + g * 16 + c] = H;
  p[tile * 128 + 64 + g * 16 + c] = L;
}

// --- prep: blocks 0..63 emb rows; 64..95 z transpose; 96..160 zero avg/scal ---
__global__ __launch_bounds__(256) void k_prep(const float* __restrict__ emb,
    const float* __restrict__ z, float* __restrict__ embn,
    float* __restrict__ ses2, float* __restrict__ zf, float* __restrict__ a02,
    short* __restrict__ ehl, short* __restrict__ zhl, float* __restrict__ avg,
    float* __restrict__ scal) {
  if (blockIdx.x < 64) {
    int n = blockIdx.x * 256 + threadIdx.x;
    const float4* r4 = (const float4*)(emb + (size_t)n * ED);
    float4 v[8]; float s = 0.f;
#pragma unroll
    for (int j = 0; j < 8; ++j) {
      v[j] = r4[j];
      s = fmaf(v[j].x, v[j].x, s); s = fmaf(v[j].y, v[j].y, s);
      s = fmaf(v[j].z, v[j].z, s); s = fmaf(v[j].w, v[j].w, s);
    }
    float inv = 1.0f / fmaxf(sqrtf(s), 1e-12f);
    float s2 = 0.f;
    float4* o4 = (float4*)(embn + (size_t)n * ED);
#pragma unroll
    for (int j = 0; j < 8; ++j) {
      float4 w; w.x = v[j].x * inv; w.y = v[j].y * inv;
      w.z = v[j].z * inv; w.w = v[j].w * inv;
      o4[j] = w; v[j] = w;
      s2 = fmaf(w.x, w.x, s2); s2 = fmaf(w.y, w.y, s2);
      s2 = fmaf(w.z, w.z, s2); s2 = fmaf(w.w, w.w, s2);
    }
    ses2[n] = NS2F * s2;               // true value, for the exact refine
#pragma unroll
    for (int g = 0; g < 4; ++g)
      split_store_t(ehl, n, g, v[2 * g], v[2 * g + 1], 1.0f);
  } else if (blockIdx.x < 96) {
    int t = (blockIdx.x - 64) * 256 + threadIdx.x;
    int b = t >> 8, hw = t & 255;
    const float* base = z + (size_t)b * (ED * 256) + hw;
    float4 v[8]; float s = 0.f;
#pragma unroll
    for (int j = 0; j < 8; ++j) {
      float4 w;
      w.x = base[(4 * j + 0) * 256]; w.y = base[(4 * j + 1) * 256];
      w.z = base[(4 * j + 2) * 256]; w.w = base[(4 * j + 3) * 256];
      v[j] = w;
      s = fmaf(w.x, w.x, s); s = fmaf(w.y, w.y, s);
      s = fmaf(w.z, w.z, s); s = fmaf(w.w, w.w, s);
    }
    float inv = 1.0f / fmaxf(sqrtf(s), 1e-12f);
    float s2 = 0.f;
    float4* o4 = (float4*)(zf + (size_t)t * ED);
#pragma unroll
    for (int j = 0; j < 8; ++j) {
      float4 w; w.x = v[j].x * inv; w.y = v[j].y * inv;
      w.z = v[j].z * inv; w.w = v[j].w * inv;
      o4[j] = w; v[j] = w;
      s2 = fmaf(w.x, w.x, s2); s2 = fmaf(w.y, w.y, s2);
      s2 = fmaf(w.z, w.z, s2); s2 = fmaf(w.w, w.w, s2);
    }
    a02[t] = NS2F * s2;               // only k_fin (exact refine) uses this
#pragma unroll
    for (int g = 0; g < 4; ++g)
      split_store_t(zhl, t, g, v[2 * g], v[2 * g + 1], K2);
  } else if (blockIdx.x < 160) {
    avg[(blockIdx.x - 96) * 256 + threadIdx.x] = 0.f;
  } else {
    if (threadIdx.x < 4) scal[threadIdx.x] = 0.f;  // [0]=sampE [1]=vq
  }
}

// --- pass 1: R22 geometry (block = 128 rows, 4 waves x 32 = 2 A-pairs),
//     sweeps a 1024-code split (64 tiles, 8 phases x 8), gload_lds 2x16KB
//     dbuf, const bias. Packed keys (tile<<4)|c in 10 mantissa LSBs.
//     NO Zs/exp2 in the loop (Z from candidates in k_fin); epilogue is
//     two plain float4 stores — no shuffles. ---
__global__ __launch_bounds__(256, 4) void k_pass1(
    const short* __restrict__ ehl, const short* __restrict__ zhl,
    float* __restrict__ cand1, float* __restrict__ cand2) {
  const int tid = threadIdx.x;
  const int lane = tid & 63, wv = tid >> 6;
  const int q = lane >> 4, c = lane & 15;
  const int rowbase = blockIdx.x * 128 + wv * 32;
  const int NT = (N_E / NS1) / 16;  // 64
  const int NP = NT / PHT;          // 8

  __shared__ s16x8 dbuf[2][PHT * 128];   // 2 x 16KB

  const s16x8* zg = (const s16x8*)zhl;
  const int atile = rowbase >> 4;
  s16x8 ah[2], al[2];
#pragma unroll
  for (int rg = 0; rg < 2; ++rg) {
    ah[rg] = zg[(atile + rg) * 128 + lane];
    al[rg] = zg[(atile + rg) * 128 + 64 + lane];
  }

  f32x4 bias;
#pragma unroll
  for (int r = 0; r < 4; ++r) bias[r] = BIAS1;

  float m1[2][4], m2[2][4];
#pragma unroll
  for (int rg = 0; rg < 2; ++rg)
#pragma unroll
    for (int k = 0; k < 4; ++k) { m1[rg][k] = -1e30f; m2[rg][k] = -1e30f; }

  const s16x8* eg = (const s16x8*)ehl + (size_t)(blockIdx.y * ((N_E / NS1) >> 4)) * 128;

  // stage phase 0: 16KB; wave wv covers s16x8 [wv*256, wv*256+256)
#pragma unroll
  for (int j = 0; j < 4; ++j)
    gload16(eg + wv * 256 + j * 64 + lane, &dbuf[0][wv * 256 + j * 64]);
  __syncthreads();

  for (int p = 0; p < NP; ++p) {
    if (p + 1 < NP) {
      const s16x8* gs = eg + (p + 1) * (PHT * 128);
      s16x8* lb = &dbuf[(p + 1) & 1][0];
#pragma unroll
      for (int j = 0; j < 4; ++j)
        gload16(gs + wv * 256 + j * 64 + lane, lb + wv * 256 + j * 64);
    }
    const s16x8* bb = &dbuf[p & 1][0];
#pragma unroll
    for (int tt = 0; tt < PHT; ++tt) {
      s16x8 bh = bb[tt * 128 + lane], bl = bb[tt * 128 + 64 + lane];
      const unsigned tuc = (((unsigned)(p * PHT + tt)) << 4) | (unsigned)c;
#pragma unroll
      for (int rg = 0; rg < 2; ++rg) {
        f32x4 acc = __builtin_amdgcn_mfma_f32_16x16x32_bf16(ah[rg], bh, bias, 0, 0, 0);
        acc = __builtin_amdgcn_mfma_f32_16x16x32_bf16(al[rg], bh, acc, 0, 0, 0);
        acc = __builtin_amdgcn_mfma_f32_16x16x32_bf16(ah[rg], bl, acc, 0, 0, 0);
#pragma unroll
        for (int r = 0; r < 4; ++r) {
          float key = __uint_as_float((__float_as_uint(acc[r]) & 0xFFFFFC00u) | tuc);
          m2[rg][r] = fmed3(key, m1[rg][r], m2[rg][r]);
          m1[rg][r] = fmaxf(m1[rg][r], key);
        }
      }
    }
    __syncthreads();
  }

  const int s = blockIdx.y;
#pragma unroll
  for (int rg = 0; rg < 2; ++rg) {
    float4 v1 = make_float4(m1[rg][0], m1[rg][1], m1[rg][2], m1[rg][3]);
    float4 v2 = make_float4(m2[rg][0], m2[rg][1], m2[rg][2], m2[rg][3]);
    const size_t base = (size_t)(s * 16 + c) * T + (rowbase + rg * 16 + q * 4);
    *(float4*)(cand1 + base) = v1;
    *(float4*)(cand2 + base) = v2;
  }
}

// --- fin: 512 blocks x 256 thr = 16 rows x 16 scan-groups. Per thread:
//     32 candidate keys in REGISTERS (unrolled). Scan1: top-2(+slot) +
//     Z = sum exp2(midband) + S2 = sum exp2*f. LDS reduce across groups.
//     Entropy row term = S2/Z - lZ (closed form). Scan2: avg atomics for
//     the rare dl > -36 keys. g==0 thread: exact refine -> output + vq. ---
__global__ __launch_bounds__(256) void k_fin(
    const float* __restrict__ cand1, const float* __restrict__ cand2,
    const float* __restrict__ zf, const float* __restrict__ embn,
    const float* __restrict__ ses2, const float* __restrict__ a02,
    float* __restrict__ avg, float* __restrict__ scal,
    float* __restrict__ out) {
  const int tid = threadIdx.x;
  const int rr = tid & 15;          // row within block
  const int g  = tid >> 4;          // scan group 0..15
  const int row = blockIdx.x * 16 + rr;

  __shared__ float sZ[256], sS2[256], sk1[256], sk2[256];
  __shared__ int su1[256], su2[256];
  __shared__ float slZ[16], rsE[16], rvq[16];

  float ka[16], kb[16];
  float k1 = -1e30f, k2 = -1e30f; int u1 = 0, u2 = 0;
  float Z = 0.f, S2 = 0.f;
#pragma unroll
  for (int k = 0; k < 16; ++k) {
    const int u = g * 16 + k;
    const float ca = cand1[(size_t)u * T + row];
    const float cb = cand2[(size_t)u * T + row];
    ka[k] = ca; kb[k] = cb;
    if (ca > k1) { k2 = k1; u2 = u1; k1 = ca; u1 = u; }
    else if (ca > k2) { k2 = ca; u2 = u; }
    if (cb > k1) { k2 = k1; u2 = u1; k1 = cb; u1 = u; }
    else if (cb > k2) { k2 = cb; u2 = u; }
    const float fa = midband(ca), fb = midband(cb);
    const float ea = fexp2(fa), eb = fexp2(fb);   // fb <= ~80: no overflow
    Z += ea + eb;
    S2 = fmaf(ea, fa, S2); S2 = fmaf(eb, fb, S2);
  }
  sZ[tid] = Z; sS2[tid] = S2;
  sk1[tid] = k1; sk2[tid] = k2; su1[tid] = u1; su2[tid] = u2;
  __syncthreads();
  for (int st = 8; st >= 1; st >>= 1) {
    if (g < st) {
      const int o = tid + st * 16;
      sZ[tid] += sZ[o]; sS2[tid] += sS2[o];
      const float ok1 = sk1[o], ok2 = sk2[o];
      const int ou1 = su1[o], ou2 = su2[o];
      const float a1 = sk1[tid], a2 = sk2[tid];
      const int b1 = su1[tid];
      if (a1 >= ok1) {
        if (a2 < ok1) { sk2[tid] = ok1; su2[tid] = ou1; }
      } else {
        sk1[tid] = ok1; su1[tid] = ou1;
        if (ok2 >= a1) { sk2[tid] = ok2; su2[tid] = ou2; }
        else           { sk2[tid] = a1;  su2[tid] = b1; }
      }
    }
    __syncthreads();
  }
  if (g == 0) slZ[rr] = flog2(sZ[rr]);
  __syncthreads();
  const float lZ = slZ[rr];

  // scan 2: avg atomics for significant candidates (register keys)
#pragma unroll
  for (int k = 0; k < 16; ++k) {
    const int u = g * 16 + k;
    {
      const float dl = midband(ka[k]) - lZ;
      if (dl > SKIPM) {
        const unsigned kid = __float_as_uint(ka[k]) & 1023u;
        atomicAdd(&avg[(u >> 4) * 1024 + (int)((kid >> 4) << 4) + (int)(kid & 15u)],
                  fexp2(dl));
      }
    }
    {
      const float dl = midband(kb[k]) - lZ;
      if (dl > SKIPM) {
        const unsigned kid = __float_as_uint(kb[k]) & 1023u;
        atomicAdd(&avg[(u >> 4) * 1024 + (int)((kid >> 4) << 4) + (int)(kid & 15u)],
                  fexp2(dl));
      }
    }
  }

  if (g == 0) {
    rsE[rr] = sS2[rr] / sZ[rr] - lZ;   // row entropy term = sum p*dl
    // decode top-2 candidate codes
    const unsigned kk1 = __float_as_uint(sk1[rr]) & 1023u;
    const unsigned kk2 = __float_as_uint(sk2[rr]) & 1023u;
    const int i1 = (su1[rr] >> 4) * 1024 + (int)((kk1 >> 4) << 4) + (int)(kk1 & 15u);
    const int i2 = (su2[rr] >> 4) * 1024 + (int)((kk2 >> 4) << 4) + (int)(kk2 & 15u);
    const float a02t = a02[row];

    const float4* zr4 = (const float4*)(zf + (size_t)row * ED);
    float4 z0 = zr4[0], z1 = zr4[1], z2 = zr4[2], z3 = zr4[3];
    float4 z4 = zr4[4], z5 = zr4[5], z6 = zr4[6], z7 = zr4[7];
    float d1 = dot32x(embn + (size_t)i1 * ED, z0, z1, z2, z3, z4, z5, z6, z7);
    float d2 = dot32x(embn + (size_t)i2 * ED, z0, z1, z2, z3, z4, z5, z6, z7);
    float fb1 = fmaf(K2, d1, a02t + ses2[i1]);   // exact re-rank
    float fb2 = fmaf(K2, d2, a02t + ses2[i2]);
    int bi = (fb2 > fb1 || (fb2 == fb1 && i2 < i1)) ? i2 : i1;

    const int b = row >> 8, hw = row & 255;
    float* ob = out + (size_t)b * (ED * 256) + hw;
    float ss = 0.f;
    const float4* e4 = (const float4*)(embn + (size_t)bi * ED);
#pragma unroll
    for (int j = 0; j < 8; ++j) {
      float4 qv = e4[j];
      float4 zv = (j == 0) ? z0 : (j == 1) ? z1 : (j == 2) ? z2 : (j == 3) ? z3
                : (j == 4) ? z4 : (j == 5) ? z5 : (j == 6) ? z6 : z7;
      float df;
      df = qv.x - zv.x; ss = fmaf(df, df, ss); ob[(4 * j + 0) * 256] = zv.x + (qv.x - zv.x);
      df = qv.y - zv.y; ss = fmaf(df, df, ss); ob[(4 * j + 1) * 256] = zv.y + (qv.y - zv.y);
      df = qv.z - zv.z; ss = fmaf(df, df, ss); ob[(4 * j + 2) * 256] = zv.z + (qv.z - zv.z);
      df = qv.w - zv.w; ss = fmaf(df, df, ss); ob[(4 * j + 3) * 256] = zv.w + (qv.w - zv.w);
    }
    rvq[rr] = ss;
  }
  __syncthreads();
  if (tid == 0) {
    float se = 0.f, vq = 0.f;
    for (int i = 0; i < 16; ++i) { se += rsE[i]; vq += rvq[i]; }
    atomicAdd(&scal[0], se);
    atomicAdd(&scal[1], vq);
  }
}

// --- last: 1 block; avg_entropy + final scalars. Stream order after k_fin
//     is the global barrier (no fences/counters). ---
__global__ __launch_bounds__(256) void k_last(const float* __restrict__ avg,
    const float* __restrict__ scal, float* __restrict__ out) {
  const int tid = threadIdx.x;
  __shared__ float red[256];
  float s = 0.f;
  for (int i = tid; i < N_E; i += 256) {
    float a = avg[i] * (1.0f / T);
    s += a * (flog2(a + 1e-5f) * LN2);
  }
  red[tid] = s;
  __syncthreads();
  for (int st = 128; st > 0; st >>= 1) {
    if (tid < st) red[tid] += red[tid + st];
    __syncthreads();
  }
  if (tid == 0) {
    float avg_entropy = -red[0];
    float sample_entropy = -(scal[0] * LN2) * (1.0f / T);
    float vq = scal[1] * (1.0f / (T * ED));
    out[T * ED + 0] = vq;
    out[T * ED + 1] = 0.25f * vq;
    out[T * ED + 2] = 0.1f * (sample_entropy - avg_entropy);
  }
}

extern "C" void kernel_launch(void* const* d_in, const int* in_sizes, int n_in,
                              void* d_out, int out_size, void* d_ws, size_t ws_size,
                              hipStream_t stream) {
  const float* z = (const float*)d_in[0];
  const float* emb = (const float*)d_in[1];
  float* out = (float*)d_out;
  float* w = (float*)d_ws;

  float* embn = w;                          // 524288 f
  float* ses2 = embn + 524288;              // 16384
  float* zf   = ses2 + 16384;               // 262144
  float* a02  = zf + 262144;                // 8192
  short* ehl  = (short*)(a02 + 8192);       // 1048576 sh (524288 f)
  short* zhl  = ehl + 1048576;              // 524288 sh  (262144 f)
  float* cand1 = (float*)(zhl + 524288);    // 256*T = 2097152 f
  float* cand2 = cand1 + 256 * T;           // 2097152 f
  float* avg  = cand2 + 256 * T;            // 16384
  float* scal = avg + 16384;                // 4: sampE, vq, pad, pad

  k_prep<<<161, 256, 0, stream>>>(emb, z, embn, ses2, zf, a02, ehl, zhl,
                                  avg, scal);
  k_pass1<<<dim3(T / 128, NS1), 256, 0, stream>>>(ehl, zhl, cand1, cand2);
  k_fin<<<T / 16, 256, 0, stream>>>(cand1, cand2, zf, embn, ses2, a02,
                                    avg, scal, out);
  k_last<<<1, 256, 0, stream>>>(avg, scal, out);
}